// Round 1
// baseline (2797.031 us; speedup 1.0000x reference)
//
#include <hip/hip_runtime.h>
#include <math.h>

#define BATCH 4
#define C 128
#define HW 4096
#define G 8
#define CPG 16      // channels per group
#define NH 4
#define HD 32
#define EPS 1e-5f
#define SCALE 0.08838834764831845f  // 128^-0.5

// ---------------- GroupNorm ----------------
// one block per (b,g); 1024 threads reduce 16*4096 = 65536 elements
__global__ __launch_bounds__(1024) void gn_kernel(
    const float* __restrict__ x, const float* __restrict__ w,
    const float* __restrict__ b, float* __restrict__ xn) {
  const int bg = blockIdx.x;
  const int batch = bg / G, g = bg % G;
  const int N = CPG * HW;
  const float* xp = x + ((size_t)batch * C + g * CPG) * HW;
  float* xnp = xn + ((size_t)batch * C + g * CPG) * HW;
  const int tid = threadIdx.x;

  float s = 0.f, ss = 0.f;
  for (int i = tid; i < N; i += 1024) {
    float v = xp[i];
    s += v; ss += v * v;
  }
  __shared__ float rs[16], rss[16];
  const int lane = tid & 63, wid = tid >> 6;
  #pragma unroll
  for (int off = 32; off; off >>= 1) {
    s  += __shfl_down(s, off);
    ss += __shfl_down(ss, off);
  }
  if (lane == 0) { rs[wid] = s; rss[wid] = ss; }
  __syncthreads();
  if (wid == 0) {
    s  = (lane < 16) ? rs[lane]  : 0.f;
    ss = (lane < 16) ? rss[lane] : 0.f;
    #pragma unroll
    for (int off = 8; off; off >>= 1) {
      s  += __shfl_down(s, off);
      ss += __shfl_down(ss, off);
    }
    if (lane == 0) { rs[0] = s; rss[0] = ss; }
  }
  __syncthreads();
  const float mean = rs[0] / (float)N;
  const float var  = rss[0] / (float)N - mean * mean;
  const float inv  = rsqrtf(var + EPS);

  __shared__ float ca[CPG], cb[CPG];
  if (tid < CPG) {
    float wv = w[g * CPG + tid], bv = b[g * CPG + tid];
    ca[tid] = wv * inv;
    cb[tid] = bv - mean * wv * inv;
  }
  __syncthreads();
  for (int i = tid; i < N; i += 1024) {
    int c = i >> 12;  // i / HW
    xnp[i] = fmaf(xp[i], ca[c], cb[c]);
  }
}

// ---------------- QKV 1x1 conv: (384x128) @ (128 x B*HW) ----------------
// block: 256 threads = 256 hw positions, 8 output channels each
__global__ __launch_bounds__(256) void qkv_kernel(
    const float* __restrict__ xn, const float* __restrict__ wq,
    const float* __restrict__ bq, float* __restrict__ qkv) {
  const int hw = blockIdx.x * 256 + threadIdx.x;
  const int o0 = blockIdx.y * 8;
  const int batch = blockIdx.z;
  __shared__ float ws[8 * C];
  for (int i = threadIdx.x; i < 8 * C; i += 256) ws[i] = wq[o0 * C + i];
  __syncthreads();
  const float* xp = xn + (size_t)batch * C * HW + hw;
  float acc[8];
  #pragma unroll
  for (int j = 0; j < 8; j++) acc[j] = bq[o0 + j];
  for (int c = 0; c < C; c++) {
    float xv = xp[(size_t)c * HW];
    #pragma unroll
    for (int j = 0; j < 8; j++) acc[j] = fmaf(ws[j * C + c], xv, acc[j]);
  }
  float* op = qkv + ((size_t)batch * 3 * C + o0) * HW + hw;
  #pragma unroll
  for (int j = 0; j < 8; j++) op[(size_t)j * HW] = acc[j];
}

// ---------------- Flash attention, fp32 ----------------
// grid (HW/256, B*NH); thread = one query position d. Q in regs (32),
// K/V tiles 32x32 in LDS (broadcast reads), online softmax with per-tile max.
// Output overwrites the Q region of qkv (safe: each block only reads its own
// 256 Q columns, at the start).
__global__ __launch_bounds__(256) void attn_kernel(float* __restrict__ qkv) {
  const int bh = blockIdx.y;
  const int batch = bh / NH, h = bh % NH;
  const int d = blockIdx.x * 256 + threadIdx.x;
  float* qp = qkv + ((size_t)batch * 3 * C + h * HD) * HW;
  const float* kp = qkv + ((size_t)batch * 3 * C + C + h * HD) * HW;
  const float* vp = qkv + ((size_t)batch * 3 * C + 2 * C + h * HD) * HW;

  float q[HD];
  #pragma unroll
  for (int c = 0; c < HD; c++) q[c] = qp[(size_t)c * HW + d] * SCALE;
  float o[HD];
  #pragma unroll
  for (int c = 0; c < HD; c++) o[c] = 0.f;
  float m = -1e30f, l = 0.f;

  __shared__ float Ks[HD][32];
  __shared__ float Vs[HD][32];

  for (int e0 = 0; e0 < HW; e0 += 32) {
    __syncthreads();
    // 32x32 x 2 = 2048 floats, 8 per thread, coalesced in e
    for (int i = threadIdx.x; i < HD * 32; i += 256) {
      int c = i >> 5, e = i & 31;
      Ks[c][e] = kp[(size_t)c * HW + e0 + e];
      Vs[c][e] = vp[(size_t)c * HW + e0 + e];
    }
    __syncthreads();

    float s[32];
    #pragma unroll
    for (int e = 0; e < 32; e++) {
      float sv = 0.f;
      #pragma unroll
      for (int c = 0; c < HD; c++) sv = fmaf(q[c], Ks[c][e], sv);
      s[e] = sv;
    }
    float tmax = -1e30f;
    #pragma unroll
    for (int e = 0; e < 32; e++) tmax = fmaxf(tmax, s[e]);
    float mnew = fmaxf(m, tmax);
    float alpha = __expf(m - mnew);
    l *= alpha;
    #pragma unroll
    for (int c = 0; c < HD; c++) o[c] *= alpha;
    #pragma unroll
    for (int e = 0; e < 32; e++) {
      float p = __expf(s[e] - mnew);
      l += p;
      #pragma unroll
      for (int c = 0; c < HD; c++) o[c] = fmaf(p, Vs[c][e], o[c]);
    }
    m = mnew;
  }
  const float inv = 1.f / l;
  // write O over the Q region: attno[b][h*HD+c][d]
  #pragma unroll
  for (int c = 0; c < HD; c++) qp[(size_t)c * HW + d] = o[c] * inv;
}

// ---------------- Proj + bias + residual ----------------
__global__ __launch_bounds__(256) void proj_kernel(
    const float* __restrict__ qkv /* q region = attn out (B,C,HW) */,
    const float* __restrict__ pw, const float* __restrict__ pb,
    const float* __restrict__ xn, float* __restrict__ out) {
  const int hw = blockIdx.x * 256 + threadIdx.x;
  const int o0 = blockIdx.y * 8;
  const int batch = blockIdx.z;
  __shared__ float ws[8 * C];
  for (int i = threadIdx.x; i < 8 * C; i += 256) ws[i] = pw[o0 * C + i];
  __syncthreads();
  const float* ap = qkv + (size_t)batch * 3 * C * HW + hw;  // attn out channels 0..127
  float acc[8];
  #pragma unroll
  for (int j = 0; j < 8; j++) acc[j] = pb[o0 + j];
  for (int c = 0; c < C; c++) {
    float av = ap[(size_t)c * HW];
    #pragma unroll
    for (int j = 0; j < 8; j++) acc[j] = fmaf(ws[j * C + c], av, acc[j]);
  }
  float* op = out + ((size_t)batch * C + o0) * HW + hw;
  const float* xp = xn + ((size_t)batch * C + o0) * HW + hw;
  #pragma unroll
  for (int j = 0; j < 8; j++) op[(size_t)j * HW] = acc[j] + xp[(size_t)j * HW];
}

extern "C" void kernel_launch(void* const* d_in, const int* in_sizes, int n_in,
                              void* d_out, int out_size, void* d_ws, size_t ws_size,
                              hipStream_t stream) {
  const float* x     = (const float*)d_in[0];
  const float* gn_w  = (const float*)d_in[1];
  const float* gn_b  = (const float*)d_in[2];
  const float* qkv_w = (const float*)d_in[3];
  const float* qkv_b = (const float*)d_in[4];
  const float* pw    = (const float*)d_in[5];
  const float* pb    = (const float*)d_in[6];
  float* out = (float*)d_out;

  float* xn  = (float*)d_ws;                          // B*C*HW = 2M floats
  float* qkv = xn + (size_t)BATCH * C * HW;           // B*3C*HW = 6M floats

  gn_kernel<<<dim3(BATCH * G), dim3(1024), 0, stream>>>(x, gn_w, gn_b, xn);
  qkv_kernel<<<dim3(HW / 256, 3 * C / 8, BATCH), dim3(256), 0, stream>>>(xn, qkv_w, qkv_b, qkv);
  attn_kernel<<<dim3(HW / 256, BATCH * NH), dim3(256), 0, stream>>>(qkv);
  proj_kernel<<<dim3(HW / 256, C / 8, BATCH), dim3(256), 0, stream>>>(qkv, pw, pb, xn, out);
}

// Round 2
// 296.268 us; speedup vs baseline: 9.4409x; 9.4409x over previous
//
#include <hip/hip_runtime.h>
#include <math.h>

#define BATCH 4
#define C 128
#define HW 4096
#define G 8
#define CPG 16
#define NH 4
#define HD 32
#define EPS 1e-5f
#define SCALE 0.08838834764831845f   // 128^-0.5
#define LOG2E 1.44269504088896340f

typedef unsigned int uint;
typedef unsigned short ushort;
typedef __attribute__((ext_vector_type(8))) short bf16x8;   // 8 bf16 (4 VGPRs)
typedef __attribute__((ext_vector_type(4))) float f32x4;

__device__ __forceinline__ ushort f2bf(float x) {
  uint u = __float_as_uint(x);
  u += 0x7fff + ((u >> 16) & 1);   // RNE
  return (ushort)(u >> 16);
}
__device__ __forceinline__ float bf2f(ushort h) {
  return __uint_as_float(((uint)h) << 16);
}

// ---------------- GroupNorm: writes fp32 xn (residual) + bf16 xn (GEMM input) ----------------
__global__ __launch_bounds__(1024) void gn_kernel(
    const float* __restrict__ x, const float* __restrict__ w,
    const float* __restrict__ b, float* __restrict__ xnf, ushort* __restrict__ xnb) {
  const int bg = blockIdx.x;
  const int batch = bg / G, g = bg % G;
  const int N = CPG * HW;
  const float* xp = x + ((size_t)batch * C + g * CPG) * HW;
  float* xfp = xnf + ((size_t)batch * C + g * CPG) * HW;
  ushort* xbp = xnb + ((size_t)batch * C + g * CPG) * HW;
  const int tid = threadIdx.x;

  float s = 0.f, ss = 0.f;
  for (int i = tid; i < N; i += 1024) {
    float v = xp[i];
    s += v; ss += v * v;
  }
  __shared__ float rs[16], rss[16];
  const int lane = tid & 63, wid = tid >> 6;
  #pragma unroll
  for (int off = 32; off; off >>= 1) {
    s  += __shfl_down(s, off);
    ss += __shfl_down(ss, off);
  }
  if (lane == 0) { rs[wid] = s; rss[wid] = ss; }
  __syncthreads();
  if (wid == 0) {
    s  = (lane < 16) ? rs[lane]  : 0.f;
    ss = (lane < 16) ? rss[lane] : 0.f;
    #pragma unroll
    for (int off = 8; off; off >>= 1) {
      s  += __shfl_down(s, off);
      ss += __shfl_down(ss, off);
    }
    if (lane == 0) { rs[0] = s; rss[0] = ss; }
  }
  __syncthreads();
  const float mean = rs[0] / (float)N;
  const float var  = rss[0] / (float)N - mean * mean;
  const float inv  = rsqrtf(var + EPS);

  __shared__ float ca[CPG], cb[CPG];
  if (tid < CPG) {
    float wv = w[g * CPG + tid], bv = b[g * CPG + tid];
    ca[tid] = wv * inv;
    cb[tid] = bv - mean * wv * inv;
  }
  __syncthreads();
  for (int i = tid; i < N; i += 1024) {
    int c = i >> 12;
    float y = fmaf(xp[i], ca[c], cb[c]);
    xfp[i] = y;
    xbp[i] = f2bf(y);
  }
}

// ---------------- MFMA GEMM: qkv = W(384x128) @ xn(128 x HW) per batch, bf16 in/out ----------------
// block: 4 waves; tile M=64 (16/wave) x N=64 (4 ntiles); K-steps of 32.
__global__ __launch_bounds__(256) void qkv_gemm(
    const ushort* __restrict__ xnb, const float* __restrict__ w,
    const float* __restrict__ bias, ushort* __restrict__ qkvb) {
  const int b = blockIdx.z, m0 = blockIdx.y * 64, n0 = blockIdx.x * 64;
  const int tid = threadIdx.x, lane = tid & 63, wv = tid >> 6;
  const int li = lane & 15, g = lane >> 4;
  __shared__ ushort Ws[64][40];   // [o][c], padded
  __shared__ ushort Xs[64][40];   // [n][c], padded (transposed staging)

  f32x4 acc[4];
  #pragma unroll
  for (int nt = 0; nt < 4; nt++) acc[nt] = (f32x4){0.f, 0.f, 0.f, 0.f};

  const int oW = tid >> 2, cW0 = (tid & 3) * 8;
  const int nX = tid & 63, cX0 = (tid >> 6) * 8;

  for (int k0 = 0; k0 < C; k0 += 32) {
    __syncthreads();
    // stage W tile (fp32 -> bf16)
    float4 wa = *(const float4*)&w[(size_t)(m0 + oW) * C + k0 + cW0];
    float4 wb = *(const float4*)&w[(size_t)(m0 + oW) * C + k0 + cW0 + 4];
    uint4 uw;
    uw.x = f2bf(wa.x) | ((uint)f2bf(wa.y) << 16);
    uw.y = f2bf(wa.z) | ((uint)f2bf(wa.w) << 16);
    uw.z = f2bf(wb.x) | ((uint)f2bf(wb.y) << 16);
    uw.w = f2bf(wb.z) | ((uint)f2bf(wb.w) << 16);
    *(uint4*)&Ws[oW][cW0] = uw;
    // stage X tile transposed: 8 strided (per-instruction coalesced) loads
    ushort tx[8];
    #pragma unroll
    for (int j = 0; j < 8; j++)
      tx[j] = xnb[(size_t)(b * C + k0 + cX0 + j) * HW + n0 + nX];
    uint4 ux;
    ux.x = tx[0] | ((uint)tx[1] << 16);
    ux.y = tx[2] | ((uint)tx[3] << 16);
    ux.z = tx[4] | ((uint)tx[5] << 16);
    ux.w = tx[6] | ((uint)tx[7] << 16);
    *(uint4*)&Xs[nX][cX0] = ux;
    __syncthreads();

    bf16x8 af = *(const bf16x8*)&Ws[wv * 16 + li][g * 8];
    #pragma unroll
    for (int nt = 0; nt < 4; nt++) {
      bf16x8 bfr = *(const bf16x8*)&Xs[nt * 16 + li][g * 8];
      acc[nt] = __builtin_amdgcn_mfma_f32_16x16x32_bf16(af, bfr, acc[nt], 0, 0, 0);
    }
  }
  const int ob = m0 + wv * 16 + g * 4;
  #pragma unroll
  for (int r = 0; r < 4; r++) {
    float bi = bias[ob + r];
    #pragma unroll
    for (int nt = 0; nt < 4; nt++) {
      qkvb[(size_t)(b * 3 * C + ob + r) * HW + n0 + nt * 16 + li] = f2bf(acc[nt][r] + bi);
    }
  }
}

// ---------------- MFMA flash attention (bf16, S^T formulation) ----------------
// block: 4 waves x 32 queries = 128 q; grid (HW/128, B*NH).
// S^T = K^T Q  -> each lane owns ONE query column (d = lane&15): cheap softmax.
// P -> PV B-operand layout via wave-private LDS round-trip.
// O (bf16) overwrites the block's own Q plane columns.
__global__ __launch_bounds__(256) void attn_kernel(ushort* __restrict__ qkv) {
  const int bh = blockIdx.y, b = bh >> 2, h = bh & 3;
  const int tid = threadIdx.x, lane = tid & 63, wv = tid >> 6;
  const int li = lane & 15, g = lane >> 4;
  ushort* qp = qkv + (size_t)(b * 3 * C + h * HD) * HW;
  const ushort* kp = qkv + (size_t)(b * 3 * C + C + h * HD) * HW;
  const ushort* vp = qkv + (size_t)(b * 3 * C + 2 * C + h * HD) * HW;
  const int d0 = blockIdx.x * 128 + wv * 32;

  __shared__ ushort Ks[32][40];        // [e][c] (transposed staging)
  __shared__ ushort Vs[32][40];        // [c][e] (direct staging)
  __shared__ ushort PT[4][2][16 * 40]; // per-wave, per-dtile: [d][e] padded

  // Q fragments (B-operand: lane holds d=li, c=g*8+j), prescaled by SCALE*log2(e)
  const float qs = SCALE * LOG2E;
  bf16x8 qf[2];
  #pragma unroll
  for (int dt = 0; dt < 2; dt++) {
    int d = d0 + dt * 16 + li;
    #pragma unroll
    for (int j = 0; j < 8; j++) {
      ushort rq = qp[(size_t)(g * 8 + j) * HW + d];
      ((short*)&qf[dt])[j] = (short)f2bf(bf2f(rq) * qs);
    }
  }

  f32x4 O[2][2];
  #pragma unroll
  for (int dt = 0; dt < 2; dt++)
    #pragma unroll
    for (int ct = 0; ct < 2; ct++) O[dt][ct] = (f32x4){0.f, 0.f, 0.f, 0.f};
  float mrow[2] = {-INFINITY, -INFINITY};
  float lsum[2] = {0.f, 0.f};

  const int eK = tid & 31, cK0 = (tid >> 5) * 4;  // K staging: transpose
  const int cV = tid >> 3, eV0 = (tid & 7) * 4;   // V staging: direct

  for (int e0 = 0; e0 < HW; e0 += 32) {
    __syncthreads();
    // stage K transposed: Ks[e][c]  (scalar loads coalesced per instruction)
    ushort tk[4];
    #pragma unroll
    for (int j = 0; j < 4; j++) tk[j] = kp[(size_t)(cK0 + j) * HW + e0 + eK];
    uint2 wk;
    wk.x = tk[0] | ((uint)tk[1] << 16);
    wk.y = tk[2] | ((uint)tk[3] << 16);
    *(uint2*)&Ks[eK][cK0] = wk;
    // stage V direct: Vs[c][e]
    *(uint2*)&Vs[cV][eV0] = *(const uint2*)&vp[(size_t)cV * HW + e0 + eV0];
    __syncthreads();

    bf16x8 kf0 = *(const bf16x8*)&Ks[li][g * 8];        // A: e=li,    c=g*8+j
    bf16x8 kf1 = *(const bf16x8*)&Ks[16 + li][g * 8];   // A: e=16+li
    bf16x8 vf0 = *(const bf16x8*)&Vs[li][g * 8];        // A: c=li,    e=g*8+j
    bf16x8 vf1 = *(const bf16x8*)&Vs[16 + li][g * 8];   // A: c=16+li

    #pragma unroll
    for (int dt = 0; dt < 2; dt++) {
      f32x4 z = (f32x4){0.f, 0.f, 0.f, 0.f};
      // S^T tiles: rows e = etile*16 + g*4 + r, col d = li  (log2-domain scores)
      f32x4 s0 = __builtin_amdgcn_mfma_f32_16x16x32_bf16(kf0, qf[dt], z, 0, 0, 0);
      f32x4 s1 = __builtin_amdgcn_mfma_f32_16x16x32_bf16(kf1, qf[dt], z, 0, 0, 0);

      float rm = fmaxf(fmaxf(fmaxf(s0[0], s0[1]), fmaxf(s0[2], s0[3])),
                       fmaxf(fmaxf(s1[0], s1[1]), fmaxf(s1[2], s1[3])));
      rm = fmaxf(rm, __shfl_xor(rm, 16));
      rm = fmaxf(rm, __shfl_xor(rm, 32));
      float mn = fmaxf(mrow[dt], rm);
      float al = exp2f(mrow[dt] - mn);
      mrow[dt] = mn;

      float p00 = exp2f(s0[0] - mn), p01 = exp2f(s0[1] - mn);
      float p02 = exp2f(s0[2] - mn), p03 = exp2f(s0[3] - mn);
      float p10 = exp2f(s1[0] - mn), p11 = exp2f(s1[1] - mn);
      float p12 = exp2f(s1[2] - mn), p13 = exp2f(s1[3] - mn);
      lsum[dt] = lsum[dt] * al + ((p00 + p01) + (p02 + p03)) + ((p10 + p11) + (p12 + p13));

      O[dt][0] *= al;
      O[dt][1] *= al;

      // P -> B-operand layout via wave-private LDS round trip
      ushort* pt = PT[wv][dt];
      uint2 w0, w1;
      w0.x = f2bf(p00) | ((uint)f2bf(p01) << 16);
      w0.y = f2bf(p02) | ((uint)f2bf(p03) << 16);
      w1.x = f2bf(p10) | ((uint)f2bf(p11) << 16);
      w1.y = f2bf(p12) | ((uint)f2bf(p13) << 16);
      *(uint2*)&pt[li * 40 + g * 4] = w0;           // et=0: e = g*4 + r
      *(uint2*)&pt[li * 40 + 16 + g * 4] = w1;      // et=1: e = 16 + g*4 + r
      bf16x8 pf = *(const bf16x8*)&pt[li * 40 + g * 8];  // B: d=li, e=g*8+j

      O[dt][0] = __builtin_amdgcn_mfma_f32_16x16x32_bf16(vf0, pf, O[dt][0], 0, 0, 0);
      O[dt][1] = __builtin_amdgcn_mfma_f32_16x16x32_bf16(vf1, pf, O[dt][1], 0, 0, 0);
    }
  }

  // finalize: full row-sum of l across the 4 lanes sharing d, then write O^T
  #pragma unroll
  for (int dt = 0; dt < 2; dt++) {
    float l = lsum[dt];
    l += __shfl_xor(l, 16);
    l += __shfl_xor(l, 32);
    float inv = 1.0f / l;
    #pragma unroll
    for (int ct = 0; ct < 2; ct++)
      #pragma unroll
      for (int r = 0; r < 4; r++)
        qp[(size_t)(ct * 16 + g * 4 + r) * HW + d0 + dt * 16 + li] = f2bf(O[dt][ct][r] * inv);
  }
}

// ---------------- MFMA GEMM proj + bias + residual, fp32 out ----------------
__global__ __launch_bounds__(256) void proj_gemm(
    const ushort* __restrict__ qkvb /* q-plane = attn out */, const float* __restrict__ w,
    const float* __restrict__ bias, const float* __restrict__ xnf, float* __restrict__ out) {
  const int b = blockIdx.z, m0 = blockIdx.y * 64, n0 = blockIdx.x * 64;
  const int tid = threadIdx.x, lane = tid & 63, wv = tid >> 6;
  const int li = lane & 15, g = lane >> 4;
  __shared__ ushort Ws[64][40];
  __shared__ ushort Xs[64][40];

  f32x4 acc[4];
  #pragma unroll
  for (int nt = 0; nt < 4; nt++) acc[nt] = (f32x4){0.f, 0.f, 0.f, 0.f};

  const int oW = tid >> 2, cW0 = (tid & 3) * 8;
  const int nX = tid & 63, cX0 = (tid >> 6) * 8;

  for (int k0 = 0; k0 < C; k0 += 32) {
    __syncthreads();
    float4 wa = *(const float4*)&w[(size_t)(m0 + oW) * C + k0 + cW0];
    float4 wb = *(const float4*)&w[(size_t)(m0 + oW) * C + k0 + cW0 + 4];
    uint4 uw;
    uw.x = f2bf(wa.x) | ((uint)f2bf(wa.y) << 16);
    uw.y = f2bf(wa.z) | ((uint)f2bf(wa.w) << 16);
    uw.z = f2bf(wb.x) | ((uint)f2bf(wb.y) << 16);
    uw.w = f2bf(wb.z) | ((uint)f2bf(wb.w) << 16);
    *(uint4*)&Ws[oW][cW0] = uw;
    ushort tx[8];
    #pragma unroll
    for (int j = 0; j < 8; j++)
      tx[j] = qkvb[(size_t)(b * 3 * C + k0 + cX0 + j) * HW + n0 + nX];
    uint4 ux;
    ux.x = tx[0] | ((uint)tx[1] << 16);
    ux.y = tx[2] | ((uint)tx[3] << 16);
    ux.z = tx[4] | ((uint)tx[5] << 16);
    ux.w = tx[6] | ((uint)tx[7] << 16);
    *(uint4*)&Xs[nX][cX0] = ux;
    __syncthreads();

    bf16x8 af = *(const bf16x8*)&Ws[wv * 16 + li][g * 8];
    #pragma unroll
    for (int nt = 0; nt < 4; nt++) {
      bf16x8 bfr = *(const bf16x8*)&Xs[nt * 16 + li][g * 8];
      acc[nt] = __builtin_amdgcn_mfma_f32_16x16x32_bf16(af, bfr, acc[nt], 0, 0, 0);
    }
  }
  const int ob = m0 + wv * 16 + g * 4;
  #pragma unroll
  for (int r = 0; r < 4; r++) {
    float bi = bias[ob + r];
    #pragma unroll
    for (int nt = 0; nt < 4; nt++) {
      size_t idx = (size_t)(b * C + ob + r) * HW + n0 + nt * 16 + li;
      out[idx] = acc[nt][r] + bi + xnf[idx];
    }
  }
}

extern "C" void kernel_launch(void* const* d_in, const int* in_sizes, int n_in,
                              void* d_out, int out_size, void* d_ws, size_t ws_size,
                              hipStream_t stream) {
  const float* x     = (const float*)d_in[0];
  const float* gn_w  = (const float*)d_in[1];
  const float* gn_b  = (const float*)d_in[2];
  const float* qkv_w = (const float*)d_in[3];
  const float* qkv_b = (const float*)d_in[4];
  const float* pw    = (const float*)d_in[5];
  const float* pb    = (const float*)d_in[6];
  float* out = (float*)d_out;

  float*  xnf  = (float*)d_ws;                               // 4*128*4096 f32 = 8 MB
  ushort* xnb  = (ushort*)(xnf + (size_t)BATCH * C * HW);    // bf16, 4 MB
  ushort* qkvb = xnb + (size_t)BATCH * C * HW;               // bf16, 12 MB

  gn_kernel<<<dim3(BATCH * G), dim3(1024), 0, stream>>>(x, gn_w, gn_b, xnf, xnb);
  qkv_gemm<<<dim3(HW / 64, 6, BATCH), dim3(256), 0, stream>>>(xnb, qkv_w, qkv_b, qkvb);
  attn_kernel<<<dim3(HW / 128, BATCH * NH), dim3(256), 0, stream>>>(qkvb);
  proj_gemm<<<dim3(HW / 64, 2, BATCH), dim3(256), 0, stream>>>(qkvb, pw, pb, xnf, out);
}

// Round 3
// 262.628 us; speedup vs baseline: 10.6502x; 1.1281x over previous
//
#include <hip/hip_runtime.h>
#include <math.h>

#define BATCH 4
#define C 128
#define HW 4096
#define G 8
#define CPG 16
#define NH 4
#define HD 32
#define EPS 1e-5f
#define SCALE 0.08838834764831845f   // 128^-0.5
#define LOG2E 1.44269504088896340f

typedef unsigned int uint;
typedef unsigned short ushort;
typedef __attribute__((ext_vector_type(8))) short bf16x8;   // 8 bf16 (4 VGPRs)
typedef __attribute__((ext_vector_type(4))) float f32x4;

__device__ __forceinline__ ushort f2bf(float x) {
  uint u = __float_as_uint(x);
  u += 0x7fff + ((u >> 16) & 1);   // RNE
  return (ushort)(u >> 16);
}
__device__ __forceinline__ ushort f2bf_r(float x) {   // round-half-away, 2 insts
  return (ushort)((__float_as_uint(x) + 0x8000u) >> 16);
}
__device__ __forceinline__ float bf2f(ushort h) {
  return __uint_as_float(((uint)h) << 16);
}
// pack two f32 -> bf16 pair (a in low half), round-half-away via +0x8000 + v_perm
__device__ __forceinline__ uint pk(float a, float b) {
  uint ua = __float_as_uint(a) + 0x8000u;
  uint ub = __float_as_uint(b) + 0x8000u;
  return __builtin_amdgcn_perm(ub, ua, 0x07060302);
}
__device__ __forceinline__ bf16x8 as_bf(uint4 u) {
  union { uint4 a; bf16x8 b; } x; x.a = u; return x.b;
}

// ---------------- GroupNorm: fp32 xn (residual) + bf16 xn (GEMM input) ----------------
__global__ __launch_bounds__(1024) void gn_kernel(
    const float* __restrict__ x, const float* __restrict__ w,
    const float* __restrict__ b, float* __restrict__ xnf, ushort* __restrict__ xnb) {
  const int bg = blockIdx.x;
  const int batch = bg / G, g = bg % G;
  const int N = CPG * HW;
  const float* xp = x + ((size_t)batch * C + g * CPG) * HW;
  float* xfp = xnf + ((size_t)batch * C + g * CPG) * HW;
  ushort* xbp = xnb + ((size_t)batch * C + g * CPG) * HW;
  const int tid = threadIdx.x;

  float s = 0.f, ss = 0.f;
  for (int i = tid; i < N; i += 1024) {
    float v = xp[i];
    s += v; ss += v * v;
  }
  __shared__ float rs[16], rss[16];
  const int lane = tid & 63, wid = tid >> 6;
  #pragma unroll
  for (int off = 32; off; off >>= 1) {
    s  += __shfl_down(s, off);
    ss += __shfl_down(ss, off);
  }
  if (lane == 0) { rs[wid] = s; rss[wid] = ss; }
  __syncthreads();
  if (wid == 0) {
    s  = (lane < 16) ? rs[lane]  : 0.f;
    ss = (lane < 16) ? rss[lane] : 0.f;
    #pragma unroll
    for (int off = 8; off; off >>= 1) {
      s  += __shfl_down(s, off);
      ss += __shfl_down(ss, off);
    }
    if (lane == 0) { rs[0] = s; rss[0] = ss; }
  }
  __syncthreads();
  const float mean = rs[0] / (float)N;
  const float var  = rss[0] / (float)N - mean * mean;
  const float inv  = rsqrtf(var + EPS);

  __shared__ float ca[CPG], cb[CPG];
  if (tid < CPG) {
    float wv = w[g * CPG + tid], bv = b[g * CPG + tid];
    ca[tid] = wv * inv;
    cb[tid] = bv - mean * wv * inv;
  }
  __syncthreads();
  for (int i = tid; i < N; i += 1024) {
    int c = i >> 12;
    float y = fmaf(xp[i], ca[c], cb[c]);
    xfp[i] = y;
    xbp[i] = f2bf(y);
  }
}

// ---------------- MFMA GEMM: qkv = W(384x128) @ xn(128 x HW), bf16 in/out ----------------
__global__ __launch_bounds__(256) void qkv_gemm(
    const ushort* __restrict__ xnb, const float* __restrict__ w,
    const float* __restrict__ bias, ushort* __restrict__ qkvb) {
  const int b = blockIdx.z, m0 = blockIdx.y * 64, n0 = blockIdx.x * 64;
  const int tid = threadIdx.x, lane = tid & 63, wv = tid >> 6;
  const int li = lane & 15, g = lane >> 4;
  __shared__ ushort Ws[64][40];
  __shared__ ushort Xs[64][40];

  f32x4 acc[4];
  #pragma unroll
  for (int nt = 0; nt < 4; nt++) acc[nt] = (f32x4){0.f, 0.f, 0.f, 0.f};

  const int oW = tid >> 2, cW0 = (tid & 3) * 8;
  const int nX = tid & 63, cX0 = (tid >> 6) * 8;

  for (int k0 = 0; k0 < C; k0 += 32) {
    __syncthreads();
    float4 wa = *(const float4*)&w[(size_t)(m0 + oW) * C + k0 + cW0];
    float4 wb = *(const float4*)&w[(size_t)(m0 + oW) * C + k0 + cW0 + 4];
    uint4 uw;
    uw.x = pk(wa.x, wa.y);
    uw.y = pk(wa.z, wa.w);
    uw.z = pk(wb.x, wb.y);
    uw.w = pk(wb.z, wb.w);
    *(uint4*)&Ws[oW][cW0] = uw;
    ushort tx[8];
    #pragma unroll
    for (int j = 0; j < 8; j++)
      tx[j] = xnb[(size_t)(b * C + k0 + cX0 + j) * HW + n0 + nX];
    uint4 ux;
    ux.x = tx[0] | ((uint)tx[1] << 16);
    ux.y = tx[2] | ((uint)tx[3] << 16);
    ux.z = tx[4] | ((uint)tx[5] << 16);
    ux.w = tx[6] | ((uint)tx[7] << 16);
    *(uint4*)&Xs[nX][cX0] = ux;
    __syncthreads();

    bf16x8 af = *(const bf16x8*)&Ws[wv * 16 + li][g * 8];
    #pragma unroll
    for (int nt = 0; nt < 4; nt++) {
      bf16x8 bfr = *(const bf16x8*)&Xs[nt * 16 + li][g * 8];
      acc[nt] = __builtin_amdgcn_mfma_f32_16x16x32_bf16(af, bfr, acc[nt], 0, 0, 0);
    }
  }
  const int ob = m0 + wv * 16 + g * 4;
  #pragma unroll
  for (int r = 0; r < 4; r++) {
    float bi = bias[ob + r];
    #pragma unroll
    for (int nt = 0; nt < 4; nt++) {
      qkvb[(size_t)(b * 3 * C + ob + r) * HW + n0 + nt * 16 + li] = f2bf(acc[nt][r] + bi);
    }
  }
}

// ---------------- K transpose: K[c][e] -> KT[b][h][e][c] (c contiguous) ----------------
__global__ __launch_bounds__(256) void ktrans_kernel(
    const ushort* __restrict__ qkvb, ushort* __restrict__ kt) {
  const int bh = blockIdx.y, b = bh >> 2, h = bh & 3;
  const int e0 = blockIdx.x * 64;
  const ushort* kp = qkvb + (size_t)(b * 3 * C + C + h * HD) * HW;
  ushort* ktp = kt + (size_t)bh * HW * HD;
  __shared__ ushort T[64][HD + 8];
  const int t = threadIdx.x;
  for (int i = t; i < HD * 64; i += 256) {
    int c = i >> 6, e = i & 63;
    T[e][c] = kp[(size_t)c * HW + e0 + e];
  }
  __syncthreads();
  for (int i = t; i < 64 * 8; i += 256) {
    int e = i >> 3, c4 = (i & 7) * 4;
    *(uint2*)&ktp[(size_t)(e0 + e) * HD + c4] = *(const uint2*)&T[e][c4];
  }
}

// ---------------- MFMA flash attention: no-max softmax, P stays in registers ----------------
// wave = 32 queries (2 d-tiles), wave-private, NO LDS / NO barriers.
// S^T = K^T Q  (C/D col = d = lane&15 == B-operand n), k<->e permutation sigma
// absorbs the row mismatch; V A-fragment loads use the same sigma.
// l accumulated by ones-row MFMA. O (bf16) overwrites own Q columns.
__global__ __launch_bounds__(256) void attn_kernel(
    ushort* __restrict__ qkv, const ushort* __restrict__ kt) {
  const int bh = blockIdx.y, b = bh >> 2, h = bh & 3;
  const int tid = threadIdx.x, lane = tid & 63, wv = tid >> 6;
  const int li = lane & 15, g = lane >> 4;
  ushort* qp = qkv + (size_t)(b * 3 * C + h * HD) * HW;
  const ushort* vp = qkv + (size_t)(b * 3 * C + 2 * C + h * HD) * HW;
  const ushort* ktp = kt + (size_t)bh * HW * HD;
  const int d0 = blockIdx.x * 128 + wv * 32;

  // Q B-fragments, prescaled by SCALE*log2(e)
  const float qs = SCALE * LOG2E;
  bf16x8 qf[2];
  #pragma unroll
  for (int dt = 0; dt < 2; dt++) {
    int d = d0 + dt * 16 + li;
    float qv[8];
    #pragma unroll
    for (int j = 0; j < 8; j++)
      qv[j] = bf2f(qp[(size_t)(g * 8 + j) * HW + d]) * qs;
    uint4 qu = {pk(qv[0], qv[1]), pk(qv[2], qv[3]), pk(qv[4], qv[5]), pk(qv[6], qv[7])};
    qf[dt] = as_bf(qu);
  }

  f32x4 O[2][2];
  #pragma unroll
  for (int dt = 0; dt < 2; dt++)
    #pragma unroll
    for (int ct = 0; ct < 2; ct++) O[dt][ct] = (f32x4){0.f, 0.f, 0.f, 0.f};
  f32x4 lacc[2] = {(f32x4){0.f, 0.f, 0.f, 0.f}, (f32x4){0.f, 0.f, 0.f, 0.f}};
  const uint one2 = 0x3F803F80u;
  bf16x8 ones = as_bf((uint4){one2, one2, one2, one2});

  const ushort* vr0 = vp + (size_t)li * HW;         // c = li
  const ushort* vr1 = vp + (size_t)(16 + li) * HW;  // c = 16+li
  const int vo0 = 4 * g, vo1 = 16 + 4 * g;          // sigma offsets

  // prefetch iter-0 fragments
  uint4 k0c = *(const uint4*)&ktp[(size_t)li * HD + g * 8];
  uint4 k1c = *(const uint4*)&ktp[(size_t)(16 + li) * HD + g * 8];
  uint2 v00c = *(const uint2*)&vr0[vo0];
  uint2 v01c = *(const uint2*)&vr0[vo1];
  uint2 v10c = *(const uint2*)&vr1[vo0];
  uint2 v11c = *(const uint2*)&vr1[vo1];

  for (int e0 = 0; e0 < HW; e0 += 32) {
    const int en = (e0 + 32) & (HW - 1);
    uint4 k0n = *(const uint4*)&ktp[(size_t)(en + li) * HD + g * 8];
    uint4 k1n = *(const uint4*)&ktp[(size_t)(en + 16 + li) * HD + g * 8];
    uint2 v00n = *(const uint2*)&vr0[en + vo0];
    uint2 v01n = *(const uint2*)&vr0[en + vo1];
    uint2 v10n = *(const uint2*)&vr1[en + vo0];
    uint2 v11n = *(const uint2*)&vr1[en + vo1];

    bf16x8 kf0 = as_bf(k0c);
    bf16x8 kf1 = as_bf(k1c);
    bf16x8 vf0 = as_bf((uint4){v00c.x, v00c.y, v01c.x, v01c.y});
    bf16x8 vf1 = as_bf((uint4){v10c.x, v10c.y, v11c.x, v11c.y});

    const f32x4 z = (f32x4){0.f, 0.f, 0.f, 0.f};
    #pragma unroll
    for (int dt = 0; dt < 2; dt++) {
      f32x4 s0 = __builtin_amdgcn_mfma_f32_16x16x32_bf16(kf0, qf[dt], z, 0, 0, 0);
      f32x4 s1 = __builtin_amdgcn_mfma_f32_16x16x32_bf16(kf1, qf[dt], z, 0, 0, 0);
      float p0 = exp2f(s0[0]), p1 = exp2f(s0[1]), p2 = exp2f(s0[2]), p3 = exp2f(s0[3]);
      float p4 = exp2f(s1[0]), p5 = exp2f(s1[1]), p6 = exp2f(s1[2]), p7 = exp2f(s1[3]);
      // sigma: k=g*8+{0..3} -> e=g*4+{0..3} (s0 rows); k=g*8+{4..7} -> e=16+g*4+{0..3} (s1 rows)
      uint4 pu = {pk(p0, p1), pk(p2, p3), pk(p4, p5), pk(p6, p7)};
      bf16x8 pf = as_bf(pu);
      lacc[dt] = __builtin_amdgcn_mfma_f32_16x16x32_bf16(ones, pf, lacc[dt], 0, 0, 0);
      O[dt][0] = __builtin_amdgcn_mfma_f32_16x16x32_bf16(vf0, pf, O[dt][0], 0, 0, 0);
      O[dt][1] = __builtin_amdgcn_mfma_f32_16x16x32_bf16(vf1, pf, O[dt][1], 0, 0, 0);
    }
    k0c = k0n; k1c = k1n;
    v00c = v00n; v01c = v01n; v10c = v10n; v11c = v11n;
  }

  #pragma unroll
  for (int dt = 0; dt < 2; dt++) {
    const float inv = 1.0f / lacc[dt][0];
    const int d = d0 + dt * 16 + li;
    #pragma unroll
    for (int ct = 0; ct < 2; ct++)
      #pragma unroll
      for (int r = 0; r < 4; r++)
        qp[(size_t)(ct * 16 + g * 4 + r) * HW + d] = f2bf_r(O[dt][ct][r] * inv);
  }
}

// ---------------- MFMA GEMM proj + bias + residual, fp32 out ----------------
__global__ __launch_bounds__(256) void proj_gemm(
    const ushort* __restrict__ qkvb, const float* __restrict__ w,
    const float* __restrict__ bias, const float* __restrict__ xnf, float* __restrict__ out) {
  const int b = blockIdx.z, m0 = blockIdx.y * 64, n0 = blockIdx.x * 64;
  const int tid = threadIdx.x, lane = tid & 63, wv = tid >> 6;
  const int li = lane & 15, g = lane >> 4;
  __shared__ ushort Ws[64][40];
  __shared__ ushort Xs[64][40];

  f32x4 acc[4];
  #pragma unroll
  for (int nt = 0; nt < 4; nt++) acc[nt] = (f32x4){0.f, 0.f, 0.f, 0.f};

  const int oW = tid >> 2, cW0 = (tid & 3) * 8;
  const int nX = tid & 63, cX0 = (tid >> 6) * 8;

  for (int k0 = 0; k0 < C; k0 += 32) {
    __syncthreads();
    float4 wa = *(const float4*)&w[(size_t)(m0 + oW) * C + k0 + cW0];
    float4 wb = *(const float4*)&w[(size_t)(m0 + oW) * C + k0 + cW0 + 4];
    uint4 uw;
    uw.x = pk(wa.x, wa.y);
    uw.y = pk(wa.z, wa.w);
    uw.z = pk(wb.x, wb.y);
    uw.w = pk(wb.z, wb.w);
    *(uint4*)&Ws[oW][cW0] = uw;
    ushort tx[8];
    #pragma unroll
    for (int j = 0; j < 8; j++)
      tx[j] = qkvb[(size_t)(b * 3 * C + k0 + cX0 + j) * HW + n0 + nX];
    uint4 ux;
    ux.x = tx[0] | ((uint)tx[1] << 16);
    ux.y = tx[2] | ((uint)tx[3] << 16);
    ux.z = tx[4] | ((uint)tx[5] << 16);
    ux.w = tx[6] | ((uint)tx[7] << 16);
    *(uint4*)&Xs[nX][cX0] = ux;
    __syncthreads();

    bf16x8 af = *(const bf16x8*)&Ws[wv * 16 + li][g * 8];
    #pragma unroll
    for (int nt = 0; nt < 4; nt++) {
      bf16x8 bfr = *(const bf16x8*)&Xs[nt * 16 + li][g * 8];
      acc[nt] = __builtin_amdgcn_mfma_f32_16x16x32_bf16(af, bfr, acc[nt], 0, 0, 0);
    }
  }
  const int ob = m0 + wv * 16 + g * 4;
  #pragma unroll
  for (int r = 0; r < 4; r++) {
    float bi = bias[ob + r];
    #pragma unroll
    for (int nt = 0; nt < 4; nt++) {
      size_t idx = (size_t)(b * C + ob + r) * HW + n0 + nt * 16 + li;
      out[idx] = acc[nt][r] + bi + xnf[idx];
    }
  }
}

extern "C" void kernel_launch(void* const* d_in, const int* in_sizes, int n_in,
                              void* d_out, int out_size, void* d_ws, size_t ws_size,
                              hipStream_t stream) {
  const float* x     = (const float*)d_in[0];
  const float* gn_w  = (const float*)d_in[1];
  const float* gn_b  = (const float*)d_in[2];
  const float* qkv_w = (const float*)d_in[3];
  const float* qkv_b = (const float*)d_in[4];
  const float* pw    = (const float*)d_in[5];
  const float* pb    = (const float*)d_in[6];
  float* out = (float*)d_out;

  float*  xnf  = (float*)d_ws;                               // 8 MB
  ushort* xnb  = (ushort*)(xnf + (size_t)BATCH * C * HW);    // 4 MB
  ushort* qkvb = xnb + (size_t)BATCH * C * HW;               // 12 MB
  ushort* kt   = qkvb + (size_t)BATCH * 3 * C * HW;          // 4 MB

  gn_kernel<<<dim3(BATCH * G), dim3(1024), 0, stream>>>(x, gn_w, gn_b, xnf, xnb);
  qkv_gemm<<<dim3(HW / 64, 6, BATCH), dim3(256), 0, stream>>>(xnb, qkv_w, qkv_b, qkvb);
  ktrans_kernel<<<dim3(HW / 64, BATCH * NH), dim3(256), 0, stream>>>(qkvb, kt);
  attn_kernel<<<dim3(HW / 128, BATCH * NH), dim3(256), 0, stream>>>(qkvb, kt);
  proj_gemm<<<dim3(HW / 64, 2, BATCH), dim3(256), 0, stream>>>(qkvb, pw, pb, xnf, out);
}

// Round 5
// 186.198 us; speedup vs baseline: 15.0218x; 1.4105x over previous
//
#include <hip/hip_runtime.h>
#include <math.h>

#define BATCH 4
#define C 128
#define HW 4096
#define G 8
#define CPG 16
#define NH 4
#define HD 32
#define EPS 1e-5f
#define SCALE 0.08838834764831845f   // 128^-0.5
#define LOG2E 1.44269504088896340f

typedef unsigned int uint;
typedef unsigned short ushort;
typedef __attribute__((ext_vector_type(8))) short bf16x8;   // 8 bf16 (4 VGPRs)
typedef __attribute__((ext_vector_type(4))) float f32x4;

__device__ __forceinline__ ushort f2bf(float x) {
  uint u = __float_as_uint(x);
  u += 0x7fff + ((u >> 16) & 1);   // RNE
  return (ushort)(u >> 16);
}
__device__ __forceinline__ ushort f2bf_r(float x) {   // round-half-away, 2 insts
  return (ushort)((__float_as_uint(x) + 0x8000u) >> 16);
}
__device__ __forceinline__ float bf2f(ushort h) {
  return __uint_as_float(((uint)h) << 16);
}
__device__ __forceinline__ uint pk(float a, float b) {  // 2 bf16 pack, round-half-away
  uint ua = __float_as_uint(a) + 0x8000u;
  uint ub = __float_as_uint(b) + 0x8000u;
  return __builtin_amdgcn_perm(ub, ua, 0x07060302);
}
__device__ __forceinline__ bf16x8 as_bf(uint4 u) {
  union { uint4 a; bf16x8 b; } x; x.a = u; return x.b;
}
__device__ __forceinline__ float fexp2(float x) {
#if __has_builtin(__builtin_amdgcn_exp2f)
  return __builtin_amdgcn_exp2f(x);   // raw v_exp_f32
#else
  return __exp2f(x);
#endif
}

// ---------------- GN pass 1: deterministic partials, plain stores ----------------
// block (bg, chunk): reduces 8192 floats -> one (s, ss) pair at a distinct slot.
__global__ __launch_bounds__(256) void gn_part(
    const float* __restrict__ x, float* __restrict__ stats) {
  const int bg = blockIdx.x >> 3, chunk = blockIdx.x & 7;
  const float* xp = x + (size_t)bg * (CPG * HW) + chunk * 8192;
  const int tid = threadIdx.x;
  float s = 0.f, ss = 0.f;
  #pragma unroll
  for (int j = 0; j < 8; j++) {
    float4 v = ((const float4*)xp)[j * 256 + tid];
    s += (v.x + v.y) + (v.z + v.w);
    ss += (v.x * v.x + v.y * v.y) + (v.z * v.z + v.w * v.w);
  }
  #pragma unroll
  for (int off = 32; off; off >>= 1) {
    s  += __shfl_down(s, off);
    ss += __shfl_down(ss, off);
  }
  __shared__ float rs[4], rss[4];
  const int lane = tid & 63, wid = tid >> 6;
  if (lane == 0) { rs[wid] = s; rss[wid] = ss; }
  __syncthreads();
  if (tid == 0) {
    stats[(bg * 8 + chunk) * 2]     = (rs[0] + rs[1]) + (rs[2] + rs[3]);
    stats[(bg * 8 + chunk) * 2 + 1] = (rss[0] + rss[1]) + (rss[2] + rss[3]);
  }
}

// ---------------- GN pass 2: reduce 8 partials, normalize, write bf16 xn ----------------
__global__ __launch_bounds__(256) void gn_apply(
    const float* __restrict__ x, const float* __restrict__ w,
    const float* __restrict__ b, const float* __restrict__ stats,
    ushort* __restrict__ xnb) {
  const int c = blockIdx.x, batch = blockIdx.y;
  const int bg = batch * G + (c >> 4);
  float s = 0.f, ss = 0.f;
  #pragma unroll
  for (int k = 0; k < 8; k++) {
    s  += stats[(bg * 8 + k) * 2];
    ss += stats[(bg * 8 + k) * 2 + 1];
  }
  const float mean = s * (1.0f / 65536.0f);
  const float var  = ss * (1.0f / 65536.0f) - mean * mean;
  const float inv  = rsqrtf(var + EPS);
  const float ca = w[c] * inv;
  const float cb = b[c] - mean * ca;
  const size_t base = ((size_t)batch * C + c) * HW;
  const float* xp = x + base;
  ushort* op = xnb + base;
  const int tid = threadIdx.x;
  #pragma unroll
  for (int j = 0; j < 4; j++) {
    int i = (j * 256 + tid) * 4;
    float4 v = *(const float4*)&xp[i];
    uint2 u;
    u.x = pk(fmaf(v.x, ca, cb), fmaf(v.y, ca, cb));
    u.y = pk(fmaf(v.z, ca, cb), fmaf(v.w, ca, cb));
    *(uint2*)&op[i] = u;
  }
}

// ---------------- MFMA GEMM: qkv = W(384x128) @ xn(128 x HW), bf16 in/out ----------------
__global__ __launch_bounds__(256) void qkv_gemm(
    const ushort* __restrict__ xnb, const float* __restrict__ w,
    const float* __restrict__ bias, ushort* __restrict__ qkvb) {
  const int b = blockIdx.z, m0 = blockIdx.y * 64, n0 = blockIdx.x * 64;
  const int tid = threadIdx.x, lane = tid & 63, wv = tid >> 6;
  const int li = lane & 15, g = lane >> 4;
  __shared__ ushort Ws[64][40];
  __shared__ ushort Xs[64][40];

  f32x4 acc[4];
  #pragma unroll
  for (int nt = 0; nt < 4; nt++) acc[nt] = (f32x4){0.f, 0.f, 0.f, 0.f};

  const int oW = tid >> 2, cW0 = (tid & 3) * 8;
  const int nX = tid & 63, cX0 = (tid >> 6) * 8;

  for (int k0 = 0; k0 < C; k0 += 32) {
    __syncthreads();
    float4 wa = *(const float4*)&w[(size_t)(m0 + oW) * C + k0 + cW0];
    float4 wb = *(const float4*)&w[(size_t)(m0 + oW) * C + k0 + cW0 + 4];
    uint4 uw = {pk(wa.x, wa.y), pk(wa.z, wa.w), pk(wb.x, wb.y), pk(wb.z, wb.w)};
    *(uint4*)&Ws[oW][cW0] = uw;
    ushort tx[8];
    #pragma unroll
    for (int j = 0; j < 8; j++)
      tx[j] = xnb[(size_t)(b * C + k0 + cX0 + j) * HW + n0 + nX];
    uint4 ux;
    ux.x = tx[0] | ((uint)tx[1] << 16);
    ux.y = tx[2] | ((uint)tx[3] << 16);
    ux.z = tx[4] | ((uint)tx[5] << 16);
    ux.w = tx[6] | ((uint)tx[7] << 16);
    *(uint4*)&Xs[nX][cX0] = ux;
    __syncthreads();

    bf16x8 af = *(const bf16x8*)&Ws[wv * 16 + li][g * 8];
    #pragma unroll
    for (int nt = 0; nt < 4; nt++) {
      bf16x8 bfr = *(const bf16x8*)&Xs[nt * 16 + li][g * 8];
      acc[nt] = __builtin_amdgcn_mfma_f32_16x16x32_bf16(af, bfr, acc[nt], 0, 0, 0);
    }
  }
  const int ob = m0 + wv * 16 + g * 4;
  #pragma unroll
  for (int r = 0; r < 4; r++) {
    float bi = bias[ob + r];
    #pragma unroll
    for (int nt = 0; nt < 4; nt++) {
      qkvb[(size_t)(b * 3 * C + ob + r) * HW + n0 + nt * 16 + li] = f2bf(acc[nt][r] + bi);
    }
  }
}

// ---------------- K/V prep: KT[bh][e][c]  +  sigma-permuted VP[bh][c][e] ----------------
// sigma (within each 32-key block): out pos p = 8*g + j  <-  e = (j<4 ? 4g+j : 16+4g+j-4)
__global__ __launch_bounds__(256) void kvprep_kernel(
    const ushort* __restrict__ qkvb, ushort* __restrict__ kt, ushort* __restrict__ vp) {
  const int bh = blockIdx.y, b = bh >> 2, h = bh & 3;
  const int e0 = blockIdx.x * 64;
  const ushort* kp = qkvb + (size_t)(b * 3 * C + C + h * HD) * HW;
  const ushort* vs = qkvb + (size_t)(b * 3 * C + 2 * C + h * HD) * HW;
  ushort* ktp = kt + (size_t)bh * HW * HD;
  ushort* vpp = vp + (size_t)bh * HD * HW;
  const int t = threadIdx.x;

  // --- K: direct register transpose, coalesced loads + 64B-row scalar stores ---
  {
    const int c = t & 31, e8 = (t >> 5) * 8;
    uint4 kv = *(const uint4*)&kp[(size_t)c * HW + e0 + e8];
    const ushort* ks = (const ushort*)&kv;
    #pragma unroll
    for (int j = 0; j < 8; j++)
      ktp[(size_t)(e0 + e8 + j) * HD + c] = ks[j];
  }

  // --- V: LDS tile then sigma-permuted vector writes ---
  __shared__ ushort Vt[32][66];
  {
    const int c = t >> 3, e8 = (t & 7) * 8;
    *(uint4*)&Vt[c][e8] = *(const uint4*)&vs[(size_t)c * HW + e0 + e8];
  }
  __syncthreads();
  {
    const int c = t >> 3, seg = t & 7, bb = seg >> 2, gt = seg & 3;
    ushort o[8];
    #pragma unroll
    for (int j = 0; j < 8; j++) {
      int el = bb * 32 + (j < 4 ? 4 * gt + j : 16 + 4 * gt + (j - 4));
      o[j] = Vt[c][el];
    }
    uint4 u;
    u.x = o[0] | ((uint)o[1] << 16);
    u.y = o[2] | ((uint)o[3] << 16);
    u.z = o[4] | ((uint)o[5] << 16);
    u.w = o[6] | ((uint)o[7] << 16);
    *(uint4*)&vpp[(size_t)c * HW + e0 + bb * 32 + gt * 8] = u;
  }
}

// ---------------- MFMA flash attention: split-K 2-way, raw exp2, reg-resident P ----------------
// block = 4 waves; waves (2p, 2p+1) share 32 queries (pair p), each does 2048 keys.
// No-max softmax: merge = add (O, l). O (bf16) overwrites own Q columns.
// Prefetch index wraps within the wave's 2048-key range: never OOB.
__global__ __launch_bounds__(256) void attn_kernel(
    ushort* __restrict__ qkv, const ushort* __restrict__ kt, const ushort* __restrict__ vp) {
  const int bh = blockIdx.y, b = bh >> 2, h = bh & 3;
  const int tid = threadIdx.x, lane = tid & 63, wv = tid >> 6;
  const int li = lane & 15, g = lane >> 4;
  const int pair = wv >> 1, half = wv & 1;
  ushort* qp = qkv + (size_t)(b * 3 * C + h * HD) * HW;
  const ushort* ktp = kt + (size_t)bh * HW * HD;
  const ushort* vpp = vp + (size_t)bh * HD * HW;
  const int d0 = blockIdx.x * 64 + pair * 32;
  const int eb = half * 2048;

  // Q B-fragments, prescaled by SCALE*log2(e)
  const float qs = SCALE * LOG2E;
  bf16x8 qf[2];
  #pragma unroll
  for (int dt = 0; dt < 2; dt++) {
    int d = d0 + dt * 16 + li;
    float qv[8];
    #pragma unroll
    for (int j = 0; j < 8; j++)
      qv[j] = bf2f(qp[(size_t)(g * 8 + j) * HW + d]) * qs;
    uint4 qu = {pk(qv[0], qv[1]), pk(qv[2], qv[3]), pk(qv[4], qv[5]), pk(qv[6], qv[7])};
    qf[dt] = as_bf(qu);
  }

  f32x4 O[2][2];
  #pragma unroll
  for (int dt = 0; dt < 2; dt++)
    #pragma unroll
    for (int ct = 0; ct < 2; ct++) O[dt][ct] = (f32x4){0.f, 0.f, 0.f, 0.f};
  f32x4 lacc[2] = {(f32x4){0.f, 0.f, 0.f, 0.f}, (f32x4){0.f, 0.f, 0.f, 0.f}};
  const uint one2 = 0x3F803F80u;
  const bf16x8 ones = as_bf((uint4){one2, one2, one2, one2});

  const ushort* vr0 = vpp + (size_t)li * HW + g * 8;
  const ushort* vr1 = vpp + (size_t)(16 + li) * HW + g * 8;

  uint4 k0c = *(const uint4*)&ktp[(size_t)(eb + li) * HD + g * 8];
  uint4 k1c = *(const uint4*)&ktp[(size_t)(eb + 16 + li) * HD + g * 8];
  uint4 v0c = *(const uint4*)&vr0[eb];
  uint4 v1c = *(const uint4*)&vr1[eb];

  for (int it = 0; it < 64; it++) {
    const int en = eb + (((it + 1) & 63) << 5);   // wraps to eb on last iter: in-range, dead
    uint4 k0n = *(const uint4*)&ktp[(size_t)(en + li) * HD + g * 8];
    uint4 k1n = *(const uint4*)&ktp[(size_t)(en + 16 + li) * HD + g * 8];
    uint4 v0n = *(const uint4*)&vr0[en];
    uint4 v1n = *(const uint4*)&vr1[en];

    bf16x8 kf0 = as_bf(k0c), kf1 = as_bf(k1c);
    bf16x8 vf0 = as_bf(v0c), vf1 = as_bf(v1c);

    const f32x4 z = (f32x4){0.f, 0.f, 0.f, 0.f};
    #pragma unroll
    for (int dt = 0; dt < 2; dt++) {
      f32x4 s0 = __builtin_amdgcn_mfma_f32_16x16x32_bf16(kf0, qf[dt], z, 0, 0, 0);
      f32x4 s1 = __builtin_amdgcn_mfma_f32_16x16x32_bf16(kf1, qf[dt], z, 0, 0, 0);
      float p0 = fexp2(s0[0]), p1 = fexp2(s0[1]), p2 = fexp2(s0[2]), p3 = fexp2(s0[3]);
      float p4 = fexp2(s1[0]), p5 = fexp2(s1[1]), p6 = fexp2(s1[2]), p7 = fexp2(s1[3]);
      uint4 pu = {pk(p0, p1), pk(p2, p3), pk(p4, p5), pk(p6, p7)};
      bf16x8 pf = as_bf(pu);
      lacc[dt] = __builtin_amdgcn_mfma_f32_16x16x32_bf16(ones, pf, lacc[dt], 0, 0, 0);
      O[dt][0] = __builtin_amdgcn_mfma_f32_16x16x32_bf16(vf0, pf, O[dt][0], 0, 0, 0);
      O[dt][1] = __builtin_amdgcn_mfma_f32_16x16x32_bf16(vf1, pf, O[dt][1], 0, 0, 0);
    }
    k0c = k0n; k1c = k1n; v0c = v0n; v1c = v1n;
  }

  // ---- split-K merge: exchange partials with partner wave, then write ct==half ----
  __shared__ float OP[4][64][19];   // 16 O + 2 l (pitch 19: odd -> conflict-free)
  #pragma unroll
  for (int dt = 0; dt < 2; dt++) {
    #pragma unroll
    for (int ct = 0; ct < 2; ct++)
      #pragma unroll
      for (int r = 0; r < 4; r++) OP[wv][lane][dt * 8 + ct * 4 + r] = O[dt][ct][r];
    OP[wv][lane][16 + dt] = lacc[dt][0];
  }
  __syncthreads();
  const int pw = wv ^ 1;
  #pragma unroll
  for (int dt = 0; dt < 2; dt++) {
    const float inv = 1.0f / (lacc[dt][0] + OP[pw][lane][16 + dt]);
    const int d = d0 + dt * 16 + li;
    #pragma unroll
    for (int r = 0; r < 4; r++) {
      float val = O[dt][half][r] + OP[pw][lane][dt * 8 + half * 4 + r];
      qp[(size_t)(half * 16 + g * 4 + r) * HW + d] = f2bf_r(val * inv);
    }
  }
}

// ---------------- MFMA GEMM proj + bias + bf16 residual, fp32 out ----------------
__global__ __launch_bounds__(256) void proj_gemm(
    const ushort* __restrict__ qkvb, const float* __restrict__ w,
    const float* __restrict__ bias, const ushort* __restrict__ xnb, float* __restrict__ out) {
  const int b = blockIdx.z, m0 = blockIdx.y * 64, n0 = blockIdx.x * 64;
  const int tid = threadIdx.x, lane = tid & 63, wv = tid >> 6;
  const int li = lane & 15, g = lane >> 4;
  __shared__ ushort Ws[64][40];
  __shared__ ushort Xs[64][40];

  f32x4 acc[4];
  #pragma unroll
  for (int nt = 0; nt < 4; nt++) acc[nt] = (f32x4){0.f, 0.f, 0.f, 0.f};

  const int oW = tid >> 2, cW0 = (tid & 3) * 8;
  const int nX = tid & 63, cX0 = (tid >> 6) * 8;

  for (int k0 = 0; k0 < C; k0 += 32) {
    __syncthreads();
    float4 wa = *(const float4*)&w[(size_t)(m0 + oW) * C + k0 + cW0];
    float4 wb = *(const float4*)&w[(size_t)(m0 + oW) * C + k0 + cW0 + 4];
    uint4 uw = {pk(wa.x, wa.y), pk(wa.z, wa.w), pk(wb.x, wb.y), pk(wb.z, wb.w)};
    *(uint4*)&Ws[oW][cW0] = uw;
    ushort tx[8];
    #pragma unroll
    for (int j = 0; j < 8; j++)
      tx[j] = qkvb[(size_t)(b * 3 * C + k0 + cX0 + j) * HW + n0 + nX];
    uint4 ux;
    ux.x = tx[0] | ((uint)tx[1] << 16);
    ux.y = tx[2] | ((uint)tx[3] << 16);
    ux.z = tx[4] | ((uint)tx[5] << 16);
    ux.w = tx[6] | ((uint)tx[7] << 16);
    *(uint4*)&Xs[nX][cX0] = ux;
    __syncthreads();

    bf16x8 af = *(const bf16x8*)&Ws[wv * 16 + li][g * 8];
    #pragma unroll
    for (int nt = 0; nt < 4; nt++) {
      bf16x8 bfr = *(const bf16x8*)&Xs[nt * 16 + li][g * 8];
      acc[nt] = __builtin_amdgcn_mfma_f32_16x16x32_bf16(af, bfr, acc[nt], 0, 0, 0);
    }
  }
  const int ob = m0 + wv * 16 + g * 4;
  #pragma unroll
  for (int r = 0; r < 4; r++) {
    float bi = bias[ob + r];
    #pragma unroll
    for (int nt = 0; nt < 4; nt++) {
      size_t idx = (size_t)(b * C + ob + r) * HW + n0 + nt * 16 + li;
      out[idx] = acc[nt][r] + bi + bf2f(xnb[idx]);
    }
  }
}

extern "C" void kernel_launch(void* const* d_in, const int* in_sizes, int n_in,
                              void* d_out, int out_size, void* d_ws, size_t ws_size,
                              hipStream_t stream) {
  const float* x     = (const float*)d_in[0];
  const float* gn_w  = (const float*)d_in[1];
  const float* gn_b  = (const float*)d_in[2];
  const float* qkv_w = (const float*)d_in[3];
  const float* qkv_b = (const float*)d_in[4];
  const float* pw    = (const float*)d_in[5];
  const float* pb    = (const float*)d_in[6];
  float* out = (float*)d_out;

  float*  stats = (float*)d_ws;                              // 512 floats (pad to 4 KB)
  ushort* xnb   = (ushort*)((char*)d_ws + 4096);             // 4 MB  bf16 [b][c][hw]
  ushort* qkvb  = xnb + (size_t)BATCH * C * HW;              // 12 MB bf16
  ushort* kt    = qkvb + (size_t)BATCH * 3 * C * HW;         // 4 MB  [bh][e][c]
  ushort* vp    = kt + (size_t)BATCH * NH * HW * HD;         // 4 MB  [bh][c][e] sigma-permuted

  gn_part<<<dim3(256), dim3(256), 0, stream>>>(x, stats);
  gn_apply<<<dim3(C, BATCH), dim3(256), 0, stream>>>(x, gn_w, gn_b, stats, xnb);
  qkv_gemm<<<dim3(HW / 64, 6, BATCH), dim3(256), 0, stream>>>(xnb, qkv_w, qkv_b, qkvb);
  kvprep_kernel<<<dim3(HW / 64, BATCH * NH), dim3(256), 0, stream>>>(qkvb, kt, vp);
  attn_kernel<<<dim3(HW / 64, BATCH * NH), dim3(256), 0, stream>>>(qkvb, kt, vp);
  proj_gemm<<<dim3(HW / 64, 2, BATCH), dim3(256), 0, stream>>>(qkvb, pw, pb, xnb, out);
}

// Round 6
// 185.642 us; speedup vs baseline: 15.0668x; 1.0030x over previous
//
#include <hip/hip_runtime.h>
#include <math.h>

#define BATCH 4
#define C 128
#define HW 4096
#define G 8
#define CPG 16
#define NH 4
#define HD 32
#define EPS 1e-5f
#define SCALE 0.08838834764831845f   // 128^-0.5
#define LOG2E 1.44269504088896340f

typedef unsigned int uint;
typedef unsigned short ushort;
typedef __attribute__((ext_vector_type(8))) short bf16x8;   // 8 bf16 (4 VGPRs)
typedef __attribute__((ext_vector_type(4))) float f32x4;

__device__ __forceinline__ ushort f2bf(float x) {
  uint u = __float_as_uint(x);
  u += 0x7fff + ((u >> 16) & 1);   // RNE
  return (ushort)(u >> 16);
}
__device__ __forceinline__ ushort f2bf_r(float x) {   // round-half-away, 2 insts
  return (ushort)((__float_as_uint(x) + 0x8000u) >> 16);
}
__device__ __forceinline__ float bf2f(ushort h) {
  return __uint_as_float(((uint)h) << 16);
}
__device__ __forceinline__ uint pk(float a, float b) {  // 2 bf16 pack, round-half-away
  uint ua = __float_as_uint(a) + 0x8000u;
  uint ub = __float_as_uint(b) + 0x8000u;
  return __builtin_amdgcn_perm(ub, ua, 0x07060302);
}
__device__ __forceinline__ bf16x8 as_bf(uint4 u) {
  union { uint4 a; bf16x8 b; } x; x.a = u; return x.b;
}
__device__ __forceinline__ float fexp2(float x) {
#if __has_builtin(__builtin_amdgcn_exp2f)
  return __builtin_amdgcn_exp2f(x);   // raw v_exp_f32
#else
  return __exp2f(x);
#endif
}

// ---------------- GN pass 1: deterministic partials, plain stores ----------------
__global__ __launch_bounds__(256) void gn_part(
    const float* __restrict__ x, float* __restrict__ stats) {
  const int bg = blockIdx.x >> 3, chunk = blockIdx.x & 7;
  const float* xp = x + (size_t)bg * (CPG * HW) + chunk * 8192;
  const int tid = threadIdx.x;
  float s = 0.f, ss = 0.f;
  #pragma unroll
  for (int j = 0; j < 8; j++) {
    float4 v = ((const float4*)xp)[j * 256 + tid];
    s += (v.x + v.y) + (v.z + v.w);
    ss += (v.x * v.x + v.y * v.y) + (v.z * v.z + v.w * v.w);
  }
  #pragma unroll
  for (int off = 32; off; off >>= 1) {
    s  += __shfl_down(s, off);
    ss += __shfl_down(ss, off);
  }
  __shared__ float rs[4], rss[4];
  const int lane = tid & 63, wid = tid >> 6;
  if (lane == 0) { rs[wid] = s; rss[wid] = ss; }
  __syncthreads();
  if (tid == 0) {
    stats[(bg * 8 + chunk) * 2]     = (rs[0] + rs[1]) + (rs[2] + rs[3]);
    stats[(bg * 8 + chunk) * 2 + 1] = (rss[0] + rss[1]) + (rss[2] + rss[3]);
  }
}

// ---------------- GN pass 2: reduce 8 partials, normalize, write bf16 xn ----------------
__global__ __launch_bounds__(256) void gn_apply(
    const float* __restrict__ x, const float* __restrict__ w,
    const float* __restrict__ b, const float* __restrict__ stats,
    ushort* __restrict__ xnb) {
  const int c = blockIdx.x, batch = blockIdx.y;
  const int bg = batch * G + (c >> 4);
  float s = 0.f, ss = 0.f;
  #pragma unroll
  for (int k = 0; k < 8; k++) {
    s  += stats[(bg * 8 + k) * 2];
    ss += stats[(bg * 8 + k) * 2 + 1];
  }
  const float mean = s * (1.0f / 65536.0f);
  const float var  = ss * (1.0f / 65536.0f) - mean * mean;
  const float inv  = rsqrtf(var + EPS);
  const float ca = w[c] * inv;
  const float cb = b[c] - mean * ca;
  const size_t base = ((size_t)batch * C + c) * HW;
  const float* xp = x + base;
  ushort* op = xnb + base;
  const int tid = threadIdx.x;
  #pragma unroll
  for (int j = 0; j < 4; j++) {
    int i = (j * 256 + tid) * 4;
    float4 v = *(const float4*)&xp[i];
    uint2 u;
    u.x = pk(fmaf(v.x, ca, cb), fmaf(v.y, ca, cb));
    u.y = pk(fmaf(v.z, ca, cb), fmaf(v.w, ca, cb));
    *(uint2*)&op[i] = u;
  }
}

// ---------------- MFMA GEMM: qkv = W(384x128) @ xn(128 x HW), bf16 in/out ----------------
__global__ __launch_bounds__(256) void qkv_gemm(
    const ushort* __restrict__ xnb, const float* __restrict__ w,
    const float* __restrict__ bias, ushort* __restrict__ qkvb) {
  const int b = blockIdx.z, m0 = blockIdx.y * 64, n0 = blockIdx.x * 64;
  const int tid = threadIdx.x, lane = tid & 63, wv = tid >> 6;
  const int li = lane & 15, g = lane >> 4;
  __shared__ ushort Ws[64][40];
  __shared__ ushort Xs[64][40];

  f32x4 acc[4];
  #pragma unroll
  for (int nt = 0; nt < 4; nt++) acc[nt] = (f32x4){0.f, 0.f, 0.f, 0.f};

  const int oW = tid >> 2, cW0 = (tid & 3) * 8;
  const int nX = tid & 63, cX0 = (tid >> 6) * 8;

  for (int k0 = 0; k0 < C; k0 += 32) {
    __syncthreads();
    float4 wa = *(const float4*)&w[(size_t)(m0 + oW) * C + k0 + cW0];
    float4 wb = *(const float4*)&w[(size_t)(m0 + oW) * C + k0 + cW0 + 4];
    uint4 uw = {pk(wa.x, wa.y), pk(wa.z, wa.w), pk(wb.x, wb.y), pk(wb.z, wb.w)};
    *(uint4*)&Ws[oW][cW0] = uw;
    ushort tx[8];
    #pragma unroll
    for (int j = 0; j < 8; j++)
      tx[j] = xnb[(size_t)(b * C + k0 + cX0 + j) * HW + n0 + nX];
    uint4 ux;
    ux.x = tx[0] | ((uint)tx[1] << 16);
    ux.y = tx[2] | ((uint)tx[3] << 16);
    ux.z = tx[4] | ((uint)tx[5] << 16);
    ux.w = tx[6] | ((uint)tx[7] << 16);
    *(uint4*)&Xs[nX][cX0] = ux;
    __syncthreads();

    bf16x8 af = *(const bf16x8*)&Ws[wv * 16 + li][g * 8];
    #pragma unroll
    for (int nt = 0; nt < 4; nt++) {
      bf16x8 bfr = *(const bf16x8*)&Xs[nt * 16 + li][g * 8];
      acc[nt] = __builtin_amdgcn_mfma_f32_16x16x32_bf16(af, bfr, acc[nt], 0, 0, 0);
    }
  }
  const int ob = m0 + wv * 16 + g * 4;
  #pragma unroll
  for (int r = 0; r < 4; r++) {
    float bi = bias[ob + r];
    #pragma unroll
    for (int nt = 0; nt < 4; nt++) {
      qkvb[(size_t)(b * 3 * C + ob + r) * HW + n0 + nt * 16 + li] = f2bf(acc[nt][r] + bi);
    }
  }
}

// ---------------- K/V prep: KT[bh][e][c] + sigma-permuted VP[bh][c][e], all vectorized ----------------
// sigma (within each 32-key block): out pos p = 8*g + j  <-  e = (j<4 ? 4g+j : 16+4g+j-4)
__global__ __launch_bounds__(256) void kvprep_kernel(
    const ushort* __restrict__ qkvb, ushort* __restrict__ kt, ushort* __restrict__ vp) {
  const int bh = blockIdx.y, b = bh >> 2, h = bh & 3;
  const int e0 = blockIdx.x * 64;
  const ushort* kp = qkvb + (size_t)(b * 3 * C + C + h * HD) * HW;
  const ushort* vs = qkvb + (size_t)(b * 3 * C + 2 * C + h * HD) * HW;
  ushort* ktp = kt + (size_t)bh * HW * HD;
  ushort* vpp = vp + (size_t)bh * HD * HW;
  const int t = threadIdx.x;

  __shared__ ushort Kt[32][66];
  __shared__ ushort Vt[32][66];
  {
    const int c = t >> 3, e8 = (t & 7) * 8;
    *(uint4*)&Kt[c][e8] = *(const uint4*)&kp[(size_t)c * HW + e0 + e8];
    *(uint4*)&Vt[c][e8] = *(const uint4*)&vs[(size_t)c * HW + e0 + e8];
  }
  __syncthreads();

  // --- K out: [e][c], one uint4 store per thread, coalesced ---
  {
    const int e = t >> 2, c0 = (t & 3) * 8;
    ushort o[8];
    #pragma unroll
    for (int j = 0; j < 8; j++) o[j] = Kt[c0 + j][e];
    uint4 u;
    u.x = o[0] | ((uint)o[1] << 16);
    u.y = o[2] | ((uint)o[3] << 16);
    u.z = o[4] | ((uint)o[5] << 16);
    u.w = o[6] | ((uint)o[7] << 16);
    *(uint4*)&ktp[(size_t)(e0 + e) * HD + c0] = u;
  }

  // --- V out: sigma-permuted [c][e], one uint4 store per thread ---
  {
    const int c = t >> 3, seg = t & 7, bb = seg >> 2, gt = seg & 3;
    ushort o[8];
    #pragma unroll
    for (int j = 0; j < 8; j++) {
      int el = bb * 32 + (j < 4 ? 4 * gt + j : 16 + 4 * gt + (j - 4));
      o[j] = Vt[c][el];
    }
    uint4 u;
    u.x = o[0] | ((uint)o[1] << 16);
    u.y = o[2] | ((uint)o[3] << 16);
    u.z = o[4] | ((uint)o[5] << 16);
    u.w = o[6] | ((uint)o[7] << 16);
    *(uint4*)&vpp[(size_t)c * HW + e0 + bb * 32 + gt * 8] = u;
  }
}

// ---------------- MFMA flash attention: split-K 4-way, raw exp2, reg-resident P ----------------
// block = 4 waves sharing 32 queries; wave wv does keys [wv*1024, wv*1024+1024).
// No-max softmax: merge = 4-way add of (O, l) via LDS; each wave writes one quarter.
// K/V loads: uniform scalar offset (saddr) + fixed lane offset. Prefetch wraps in-range.
__global__ __launch_bounds__(256) void attn_kernel(
    ushort* __restrict__ qkv, const ushort* __restrict__ kt, const ushort* __restrict__ vp) {
  const int bh = blockIdx.y, b = bh >> 2, h = bh & 3;
  const int tid = threadIdx.x, lane = tid & 63, wv = tid >> 6;
  const int li = lane & 15, g = lane >> 4;
  ushort* qp = qkv + (size_t)(b * 3 * C + h * HD) * HW;
  const ushort* ktp = kt + (size_t)bh * HW * HD;
  const ushort* vpp = vp + (size_t)bh * HD * HW;
  const int d0 = blockIdx.x * 32;
  const int eb = wv * 1024;

  // Q B-fragments, prescaled by SCALE*log2(e)
  const float qs = SCALE * LOG2E;
  bf16x8 qf[2];
  #pragma unroll
  for (int dt = 0; dt < 2; dt++) {
    int d = d0 + dt * 16 + li;
    float qv[8];
    #pragma unroll
    for (int j = 0; j < 8; j++)
      qv[j] = bf2f(qp[(size_t)(g * 8 + j) * HW + d]) * qs;
    uint4 qu = {pk(qv[0], qv[1]), pk(qv[2], qv[3]), pk(qv[4], qv[5]), pk(qv[6], qv[7])};
    qf[dt] = as_bf(qu);
  }

  f32x4 O[2][2];
  #pragma unroll
  for (int dt = 0; dt < 2; dt++)
    #pragma unroll
    for (int ct = 0; ct < 2; ct++) O[dt][ct] = (f32x4){0.f, 0.f, 0.f, 0.f};
  f32x4 lacc[2] = {(f32x4){0.f, 0.f, 0.f, 0.f}, (f32x4){0.f, 0.f, 0.f, 0.f}};
  const uint one2 = 0x3F803F80u;
  const bf16x8 ones = as_bf((uint4){one2, one2, one2, one2});

  // lane-fixed bases; per-iter offset is wave-uniform -> saddr-form loads
  const ushort* kb0 = ktp + (size_t)li * HD + g * 8;
  const ushort* kb1 = ktp + (size_t)(16 + li) * HD + g * 8;
  const ushort* vb0 = vpp + (size_t)li * HW + g * 8;
  const ushort* vb1 = vpp + (size_t)(16 + li) * HW + g * 8;

  uint4 k0c = *(const uint4*)&kb0[(size_t)eb * HD];
  uint4 k1c = *(const uint4*)&kb1[(size_t)eb * HD];
  uint4 v0c = *(const uint4*)&vb0[eb];
  uint4 v1c = *(const uint4*)&vb1[eb];

  for (int it = 0; it < 32; it++) {
    const int en = eb + (((it + 1) & 31) << 5);   // wraps to eb on last iter: in-range, dead
    uint4 k0n = *(const uint4*)&kb0[(size_t)en * HD];
    uint4 k1n = *(const uint4*)&kb1[(size_t)en * HD];
    uint4 v0n = *(const uint4*)&vb0[en];
    uint4 v1n = *(const uint4*)&vb1[en];

    bf16x8 kf0 = as_bf(k0c), kf1 = as_bf(k1c);
    bf16x8 vf0 = as_bf(v0c), vf1 = as_bf(v1c);

    const f32x4 z = (f32x4){0.f, 0.f, 0.f, 0.f};
    #pragma unroll
    for (int dt = 0; dt < 2; dt++) {
      f32x4 s0 = __builtin_amdgcn_mfma_f32_16x16x32_bf16(kf0, qf[dt], z, 0, 0, 0);
      f32x4 s1 = __builtin_amdgcn_mfma_f32_16x16x32_bf16(kf1, qf[dt], z, 0, 0, 0);
      float p0 = fexp2(s0[0]), p1 = fexp2(s0[1]), p2 = fexp2(s0[2]), p3 = fexp2(s0[3]);
      float p4 = fexp2(s1[0]), p5 = fexp2(s1[1]), p6 = fexp2(s1[2]), p7 = fexp2(s1[3]);
      uint4 pu = {pk(p0, p1), pk(p2, p3), pk(p4, p5), pk(p6, p7)};
      bf16x8 pf = as_bf(pu);
      lacc[dt] = __builtin_amdgcn_mfma_f32_16x16x32_bf16(ones, pf, lacc[dt], 0, 0, 0);
      O[dt][0] = __builtin_amdgcn_mfma_f32_16x16x32_bf16(vf0, pf, O[dt][0], 0, 0, 0);
      O[dt][1] = __builtin_amdgcn_mfma_f32_16x16x32_bf16(vf1, pf, O[dt][1], 0, 0, 0);
    }
    k0c = k0n; k1c = k1n; v0c = v0n; v1c = v1n;
  }

  // ---- split-K 4-way merge via LDS; wave wv writes quarter (qdt, qct) ----
  __shared__ float OP[4][64][19];   // 16 O + 2 l (pitch 19: odd -> conflict-free)
  #pragma unroll
  for (int dt = 0; dt < 2; dt++) {
    #pragma unroll
    for (int ct = 0; ct < 2; ct++)
      #pragma unroll
      for (int r = 0; r < 4; r++) OP[wv][lane][dt * 8 + ct * 4 + r] = O[dt][ct][r];
    OP[wv][lane][16 + dt] = lacc[dt][0];
  }
  __syncthreads();
  const int qdt = wv >> 1, qct = wv & 1;
  float l4 = (OP[0][lane][16 + qdt] + OP[1][lane][16 + qdt]) +
             (OP[2][lane][16 + qdt] + OP[3][lane][16 + qdt]);
  const float inv = 1.0f / l4;
  const int d = d0 + qdt * 16 + li;
  #pragma unroll
  for (int r = 0; r < 4; r++) {
    const int idx = qdt * 8 + qct * 4 + r;
    float val = (OP[0][lane][idx] + OP[1][lane][idx]) +
                (OP[2][lane][idx] + OP[3][lane][idx]);
    qp[(size_t)(qct * 16 + g * 4 + r) * HW + d] = f2bf_r(val * inv);
  }
}

// ---------------- MFMA GEMM proj + bias + bf16 residual, fp32 out ----------------
__global__ __launch_bounds__(256) void proj_gemm(
    const ushort* __restrict__ qkvb, const float* __restrict__ w,
    const float* __restrict__ bias, const ushort* __restrict__ xnb, float* __restrict__ out) {
  const int b = blockIdx.z, m0 = blockIdx.y * 64, n0 = blockIdx.x * 64;
  const int tid = threadIdx.x, lane = tid & 63, wv = tid >> 6;
  const int li = lane & 15, g = lane >> 4;
  __shared__ ushort Ws[64][40];
  __shared__ ushort Xs[64][40];

  f32x4 acc[4];
  #pragma unroll
  for (int nt = 0; nt < 4; nt++) acc[nt] = (f32x4){0.f, 0.f, 0.f, 0.f};

  const int oW = tid >> 2, cW0 = (tid & 3) * 8;
  const int nX = tid & 63, cX0 = (tid >> 6) * 8;

  for (int k0 = 0; k0 < C; k0 += 32) {
    __syncthreads();
    float4 wa = *(const float4*)&w[(size_t)(m0 + oW) * C + k0 + cW0];
    float4 wb = *(const float4*)&w[(size_t)(m0 + oW) * C + k0 + cW0 + 4];
    uint4 uw = {pk(wa.x, wa.y), pk(wa.z, wa.w), pk(wb.x, wb.y), pk(wb.z, wb.w)};
    *(uint4*)&Ws[oW][cW0] = uw;
    ushort tx[8];
    #pragma unroll
    for (int j = 0; j < 8; j++)
      tx[j] = qkvb[(size_t)(b * 3 * C + k0 + cX0 + j) * HW + n0 + nX];
    uint4 ux;
    ux.x = tx[0] | ((uint)tx[1] << 16);
    ux.y = tx[2] | ((uint)tx[3] << 16);
    ux.z = tx[4] | ((uint)tx[5] << 16);
    ux.w = tx[6] | ((uint)tx[7] << 16);
    *(uint4*)&Xs[nX][cX0] = ux;
    __syncthreads();

    bf16x8 af = *(const bf16x8*)&Ws[wv * 16 + li][g * 8];
    #pragma unroll
    for (int nt = 0; nt < 4; nt++) {
      bf16x8 bfr = *(const bf16x8*)&Xs[nt * 16 + li][g * 8];
      acc[nt] = __builtin_amdgcn_mfma_f32_16x16x32_bf16(af, bfr, acc[nt], 0, 0, 0);
    }
  }
  const int ob = m0 + wv * 16 + g * 4;
  #pragma unroll
  for (int r = 0; r < 4; r++) {
    float bi = bias[ob + r];
    #pragma unroll
    for (int nt = 0; nt < 4; nt++) {
      size_t idx = (size_t)(b * C + ob + r) * HW + n0 + nt * 16 + li;
      out[idx] = acc[nt][r] + bi + bf2f(xnb[idx]);
    }
  }
}

extern "C" void kernel_launch(void* const* d_in, const int* in_sizes, int n_in,
                              void* d_out, int out_size, void* d_ws, size_t ws_size,
                              hipStream_t stream) {
  const float* x     = (const float*)d_in[0];
  const float* gn_w  = (const float*)d_in[1];
  const float* gn_b  = (const float*)d_in[2];
  const float* qkv_w = (const float*)d_in[3];
  const float* qkv_b = (const float*)d_in[4];
  const float* pw    = (const float*)d_in[5];
  const float* pb    = (const float*)d_in[6];
  float* out = (float*)d_out;

  float*  stats = (float*)d_ws;                              // 512 floats (pad to 4 KB)
  ushort* xnb   = (ushort*)((char*)d_ws + 4096);             // 4 MB  bf16 [b][c][hw]
  ushort* qkvb  = xnb + (size_t)BATCH * C * HW;              // 12 MB bf16
  ushort* kt    = qkvb + (size_t)BATCH * 3 * C * HW;         // 4 MB  [bh][e][c]
  ushort* vp    = kt + (size_t)BATCH * NH * HW * HD;         // 4 MB  [bh][c][e] sigma-permuted

  gn_part<<<dim3(256), dim3(256), 0, stream>>>(x, stats);
  gn_apply<<<dim3(C, BATCH), dim3(256), 0, stream>>>(x, gn_w, gn_b, stats, xnb);
  qkv_gemm<<<dim3(HW / 64, 6, BATCH), dim3(256), 0, stream>>>(xnb, qkv_w, qkv_b, qkvb);
  kvprep_kernel<<<dim3(HW / 64, BATCH * NH), dim3(256), 0, stream>>>(qkvb, kt, vp);
  attn_kernel<<<dim3(HW / 32, BATCH * NH), dim3(256), 0, stream>>>(qkvb, kt, vp);
  proj_gemm<<<dim3(HW / 64, 2, BATCH), dim3(256), 0, stream>>>(qkvb, pw, pb, xnb, out);
}

// Round 7
// 185.307 us; speedup vs baseline: 15.0941x; 1.0018x over previous
//
#include <hip/hip_runtime.h>
#include <math.h>

#define BATCH 4
#define C 128
#define HW 4096
#define G 8
#define CPG 16
#define NH 4
#define HD 32
#define EPS 1e-5f
#define SCALE 0.08838834764831845f   // 128^-0.5
#define LOG2E 1.44269504088896340f

typedef unsigned int uint;
typedef unsigned short ushort;
typedef __attribute__((ext_vector_type(8))) short bf16x8;   // 8 bf16 (4 VGPRs)
typedef __attribute__((ext_vector_type(4))) float f32x4;

__device__ __forceinline__ ushort f2bf(float x) {
  uint u = __float_as_uint(x);
  u += 0x7fff + ((u >> 16) & 1);   // RNE
  return (ushort)(u >> 16);
}
__device__ __forceinline__ ushort f2bf_r(float x) {   // round-half-away, 2 insts
  return (ushort)((__float_as_uint(x) + 0x8000u) >> 16);
}
__device__ __forceinline__ float bf2f(ushort h) {
  return __uint_as_float(((uint)h) << 16);
}
__device__ __forceinline__ uint pk(float a, float b) {  // 2 bf16 pack, round-half-away
  uint ua = __float_as_uint(a) + 0x8000u;
  uint ub = __float_as_uint(b) + 0x8000u;
  return __builtin_amdgcn_perm(ub, ua, 0x07060302);
}
__device__ __forceinline__ bf16x8 as_bf(uint4 u) {
  union { uint4 a; bf16x8 b; } x; x.a = u; return x.b;
}
__device__ __forceinline__ float fexp2(float x) {
#if __has_builtin(__builtin_amdgcn_exp2f)
  return __builtin_amdgcn_exp2f(x);   // raw v_exp_f32
#else
  return __exp2f(x);
#endif
}

// ---------------- GN pass 1: deterministic partials, plain stores ----------------
__global__ __launch_bounds__(256) void gn_part(
    const float* __restrict__ x, float* __restrict__ stats) {
  const int bg = blockIdx.x >> 3, chunk = blockIdx.x & 7;
  const float* xp = x + (size_t)bg * (CPG * HW) + chunk * 8192;
  const int tid = threadIdx.x;
  float s = 0.f, ss = 0.f;
  #pragma unroll
  for (int j = 0; j < 8; j++) {
    float4 v = ((const float4*)xp)[j * 256 + tid];
    s += (v.x + v.y) + (v.z + v.w);
    ss += (v.x * v.x + v.y * v.y) + (v.z * v.z + v.w * v.w);
  }
  #pragma unroll
  for (int off = 32; off; off >>= 1) {
    s  += __shfl_down(s, off);
    ss += __shfl_down(ss, off);
  }
  __shared__ float rs[4], rss[4];
  const int lane = tid & 63, wid = tid >> 6;
  if (lane == 0) { rs[wid] = s; rss[wid] = ss; }
  __syncthreads();
  if (tid == 0) {
    stats[(bg * 8 + chunk) * 2]     = (rs[0] + rs[1]) + (rs[2] + rs[3]);
    stats[(bg * 8 + chunk) * 2 + 1] = (rss[0] + rss[1]) + (rss[2] + rss[3]);
  }
}

// ---------------- GN pass 2: reduce 8 partials, normalize, write bf16 xn ----------------
__global__ __launch_bounds__(256) void gn_apply(
    const float* __restrict__ x, const float* __restrict__ w,
    const float* __restrict__ b, const float* __restrict__ stats,
    ushort* __restrict__ xnb) {
  const int c = blockIdx.x, batch = blockIdx.y;
  const int bg = batch * G + (c >> 4);
  float s = 0.f, ss = 0.f;
  #pragma unroll
  for (int k = 0; k < 8; k++) {
    s  += stats[(bg * 8 + k) * 2];
    ss += stats[(bg * 8 + k) * 2 + 1];
  }
  const float mean = s * (1.0f / 65536.0f);
  const float var  = ss * (1.0f / 65536.0f) - mean * mean;
  const float inv  = rsqrtf(var + EPS);
  const float ca = w[c] * inv;
  const float cb = b[c] - mean * ca;
  const size_t base = ((size_t)batch * C + c) * HW;
  const float* xp = x + base;
  ushort* op = xnb + base;
  const int tid = threadIdx.x;
  #pragma unroll
  for (int j = 0; j < 4; j++) {
    int i = (j * 256 + tid) * 4;
    float4 v = *(const float4*)&xp[i];
    uint2 u;
    u.x = pk(fmaf(v.x, ca, cb), fmaf(v.y, ca, cb));
    u.y = pk(fmaf(v.z, ca, cb), fmaf(v.w, ca, cb));
    *(uint2*)&op[i] = u;
  }
}

// ---------------- MFMA GEMM: qkv = W(384x128) @ xn(128 x HW), bf16 in/out ----------------
__global__ __launch_bounds__(256) void qkv_gemm(
    const ushort* __restrict__ xnb, const float* __restrict__ w,
    const float* __restrict__ bias, ushort* __restrict__ qkvb) {
  const int b = blockIdx.z, m0 = blockIdx.y * 64, n0 = blockIdx.x * 64;
  const int tid = threadIdx.x, lane = tid & 63, wv = tid >> 6;
  const int li = lane & 15, g = lane >> 4;
  __shared__ ushort Ws[64][40];
  __shared__ ushort Xs[64][40];

  f32x4 acc[4];
  #pragma unroll
  for (int nt = 0; nt < 4; nt++) acc[nt] = (f32x4){0.f, 0.f, 0.f, 0.f};

  const int oW = tid >> 2, cW0 = (tid & 3) * 8;
  const int nX = tid & 63, cX0 = (tid >> 6) * 8;

  for (int k0 = 0; k0 < C; k0 += 32) {
    __syncthreads();
    float4 wa = *(const float4*)&w[(size_t)(m0 + oW) * C + k0 + cW0];
    float4 wb = *(const float4*)&w[(size_t)(m0 + oW) * C + k0 + cW0 + 4];
    uint4 uw = {pk(wa.x, wa.y), pk(wa.z, wa.w), pk(wb.x, wb.y), pk(wb.z, wb.w)};
    *(uint4*)&Ws[oW][cW0] = uw;
    ushort tx[8];
    #pragma unroll
    for (int j = 0; j < 8; j++)
      tx[j] = xnb[(size_t)(b * C + k0 + cX0 + j) * HW + n0 + nX];
    uint4 ux;
    ux.x = tx[0] | ((uint)tx[1] << 16);
    ux.y = tx[2] | ((uint)tx[3] << 16);
    ux.z = tx[4] | ((uint)tx[5] << 16);
    ux.w = tx[6] | ((uint)tx[7] << 16);
    *(uint4*)&Xs[nX][cX0] = ux;
    __syncthreads();

    bf16x8 af = *(const bf16x8*)&Ws[wv * 16 + li][g * 8];
    #pragma unroll
    for (int nt = 0; nt < 4; nt++) {
      bf16x8 bfr = *(const bf16x8*)&Xs[nt * 16 + li][g * 8];
      acc[nt] = __builtin_amdgcn_mfma_f32_16x16x32_bf16(af, bfr, acc[nt], 0, 0, 0);
    }
  }
  const int ob = m0 + wv * 16 + g * 4;
  #pragma unroll
  for (int r = 0; r < 4; r++) {
    float bi = bias[ob + r];
    #pragma unroll
    for (int nt = 0; nt < 4; nt++) {
      qkvb[(size_t)(b * 3 * C + ob + r) * HW + n0 + nt * 16 + li] = f2bf(acc[nt][r] + bi);
    }
  }
}

// ---------------- K prep: KT[bh][e][c] (c contiguous), vectorized ----------------
__global__ __launch_bounds__(256) void kvprep_kernel(
    const ushort* __restrict__ qkvb, ushort* __restrict__ kt) {
  const int bh = blockIdx.y, b = bh >> 2, h = bh & 3;
  const int e0 = blockIdx.x * 64;
  const ushort* kp = qkvb + (size_t)(b * 3 * C + C + h * HD) * HW;
  ushort* ktp = kt + (size_t)bh * HW * HD;
  const int t = threadIdx.x;

  __shared__ ushort Kt[32][66];
  {
    const int c = t >> 3, e8 = (t & 7) * 8;
    *(uint4*)&Kt[c][e8] = *(const uint4*)&kp[(size_t)c * HW + e0 + e8];
  }
  __syncthreads();
  {
    const int e = t >> 2, c0 = (t & 3) * 8;
    ushort o[8];
    #pragma unroll
    for (int j = 0; j < 8; j++) o[j] = Kt[c0 + j][e];
    uint4 u;
    u.x = o[0] | ((uint)o[1] << 16);
    u.y = o[2] | ((uint)o[3] << 16);
    u.z = o[4] | ((uint)o[5] << 16);
    u.w = o[6] | ((uint)o[7] << 16);
    *(uint4*)&ktp[(size_t)(e0 + e) * HD + c0] = u;
  }
}

// ---------------- MFMA flash attention: LDS-shared K/V, 64 q/wave, no split-K ----------------
// block = 4 waves x 64 queries = 256 q; block iterates all 128 key-tiles.
// K/V tile (4 KB) staged once per block into double-buffered LDS; all 4 waves share.
// S^T = K^T Q; P stays in registers (sigma absorbed by V ds_read addressing).
// l accumulated by ones-row MFMA. O (bf16) overwrites own Q columns.
__global__ __launch_bounds__(256, 2) void attn_kernel(
    ushort* __restrict__ qkv, const ushort* __restrict__ kt) {
  const int bh = blockIdx.y, b = bh >> 2, h = bh & 3;
  const int tid = threadIdx.x, lane = tid & 63, wv = tid >> 6;
  const int li = lane & 15, g = lane >> 4;
  ushort* qp = qkv + (size_t)(b * 3 * C + h * HD) * HW;
  const ushort* vpl = qkv + (size_t)(b * 3 * C + 2 * C + h * HD) * HW;
  const ushort* ktp = kt + (size_t)bh * HW * HD;
  const int d0 = blockIdx.x * 256 + wv * 64;

  __shared__ ushort Ks[2][32][40];
  __shared__ ushort Vs[2][32][40];

  // Q B-fragments (4 d-tiles), prescaled by SCALE*log2(e)
  const float qs = SCALE * LOG2E;
  bf16x8 qf[4];
  #pragma unroll
  for (int dt = 0; dt < 4; dt++) {
    int d = d0 + dt * 16 + li;
    float qv[8];
    #pragma unroll
    for (int j = 0; j < 8; j++)
      qv[j] = bf2f(qp[(size_t)(g * 8 + j) * HW + d]) * qs;
    uint4 qu = {pk(qv[0], qv[1]), pk(qv[2], qv[3]), pk(qv[4], qv[5]), pk(qv[6], qv[7])};
    qf[dt] = as_bf(qu);
  }

  f32x4 O[4][2];
  #pragma unroll
  for (int dt = 0; dt < 4; dt++)
    #pragma unroll
    for (int ct = 0; ct < 2; ct++) O[dt][ct] = (f32x4){0.f, 0.f, 0.f, 0.f};
  f32x4 lacc[4];
  #pragma unroll
  for (int dt = 0; dt < 4; dt++) lacc[dt] = (f32x4){0.f, 0.f, 0.f, 0.f};
  const uint one2 = 0x3F803F80u;
  const bf16x8 ones = as_bf((uint4){one2, one2, one2, one2});

  // staging assignment: threads 0..127 stage K (2 KB contiguous from KT),
  // threads 128..255 stage V (32 rows x 64 B from the V plane)
  const bool isK = tid < 128;
  const int t2 = tid & 127;
  const int srow = t2 >> 2, scol8 = (t2 & 3) * 8;
  const ushort* gK = ktp + t2 * 8;                     // + tile*1024
  const ushort* gV = vpl + (size_t)srow * HW + scol8;  // + tile*32

  uint4 st = isK ? *(const uint4*)&gK[0] : *(const uint4*)&gV[0];
  if (isK) *(uint4*)&Ks[0][srow][scol8] = st;
  else     *(uint4*)&Vs[0][srow][scol8] = st;
  st = isK ? *(const uint4*)&gK[1024] : *(const uint4*)&gV[32];
  __syncthreads();

  for (int it = 0; it < 128; it++) {
    const int cur = it & 1, nxt = cur ^ 1;
    // store tile it+1 into the other buffer (regs loaded last iter)
    if (isK) *(uint4*)&Ks[nxt][srow][scol8] = st;
    else     *(uint4*)&Vs[nxt][srow][scol8] = st;

    // fragments from current buffer
    bf16x8 kf0 = *(const bf16x8*)&Ks[cur][li][g * 8];
    bf16x8 kf1 = *(const bf16x8*)&Ks[cur][16 + li][g * 8];
    uint2 va0 = *(const uint2*)&Vs[cur][li][4 * g];
    uint2 va1 = *(const uint2*)&Vs[cur][li][16 + 4 * g];
    uint2 vb0 = *(const uint2*)&Vs[cur][16 + li][4 * g];
    uint2 vb1 = *(const uint2*)&Vs[cur][16 + li][16 + 4 * g];
    bf16x8 vf0 = as_bf((uint4){va0.x, va0.y, va1.x, va1.y});
    bf16x8 vf1 = as_bf((uint4){vb0.x, vb0.y, vb1.x, vb1.y});

    // prefetch tile it+2 into regs (wraps in-range on last iters: dead data)
    const int tn = (it + 2) & 127;
    st = isK ? *(const uint4*)&gK[(size_t)tn * 1024] : *(const uint4*)&gV[tn * 32];

    const f32x4 z = (f32x4){0.f, 0.f, 0.f, 0.f};
    #pragma unroll
    for (int dt = 0; dt < 4; dt++) {
      f32x4 s0 = __builtin_amdgcn_mfma_f32_16x16x32_bf16(kf0, qf[dt], z, 0, 0, 0);
      f32x4 s1 = __builtin_amdgcn_mfma_f32_16x16x32_bf16(kf1, qf[dt], z, 0, 0, 0);
      float p0 = fexp2(s0[0]), p1 = fexp2(s0[1]), p2 = fexp2(s0[2]), p3 = fexp2(s0[3]);
      float p4 = fexp2(s1[0]), p5 = fexp2(s1[1]), p6 = fexp2(s1[2]), p7 = fexp2(s1[3]);
      // sigma: k=g*8+{0..3} -> e=4g+{0..3}; k=g*8+{4..7} -> e=16+4g+{0..3}
      uint4 pu = {pk(p0, p1), pk(p2, p3), pk(p4, p5), pk(p6, p7)};
      bf16x8 pf = as_bf(pu);
      lacc[dt] = __builtin_amdgcn_mfma_f32_16x16x32_bf16(ones, pf, lacc[dt], 0, 0, 0);
      O[dt][0] = __builtin_amdgcn_mfma_f32_16x16x32_bf16(vf0, pf, O[dt][0], 0, 0, 0);
      O[dt][1] = __builtin_amdgcn_mfma_f32_16x16x32_bf16(vf1, pf, O[dt][1], 0, 0, 0);
    }
    __syncthreads();
  }

  // epilogue: wave-private normalize + write O over own Q columns
  #pragma unroll
  for (int dt = 0; dt < 4; dt++) {
    const float inv = 1.0f / lacc[dt][0];
    const int d = d0 + dt * 16 + li;
    #pragma unroll
    for (int ct = 0; ct < 2; ct++)
      #pragma unroll
      for (int r = 0; r < 4; r++)
        qp[(size_t)(ct * 16 + g * 4 + r) * HW + d] = f2bf_r(O[dt][ct][r] * inv);
  }
}

// ---------------- MFMA GEMM proj + bias + bf16 residual, fp32 out ----------------
__global__ __launch_bounds__(256) void proj_gemm(
    const ushort* __restrict__ qkvb, const float* __restrict__ w,
    const float* __restrict__ bias, const ushort* __restrict__ xnb, float* __restrict__ out) {
  const int b = blockIdx.z, m0 = blockIdx.y * 64, n0 = blockIdx.x * 64;
  const int tid = threadIdx.x, lane = tid & 63, wv = tid >> 6;
  const int li = lane & 15, g = lane >> 4;
  __shared__ ushort Ws[64][40];
  __shared__ ushort Xs[64][40];

  f32x4 acc[4];
  #pragma unroll
  for (int nt = 0; nt < 4; nt++) acc[nt] = (f32x4){0.f, 0.f, 0.f, 0.f};

  const int oW = tid >> 2, cW0 = (tid & 3) * 8;
  const int nX = tid & 63, cX0 = (tid >> 6) * 8;

  for (int k0 = 0; k0 < C; k0 += 32) {
    __syncthreads();
    float4 wa = *(const float4*)&w[(size_t)(m0 + oW) * C + k0 + cW0];
    float4 wb = *(const float4*)&w[(size_t)(m0 + oW) * C + k0 + cW0 + 4];
    uint4 uw = {pk(wa.x, wa.y), pk(wa.z, wa.w), pk(wb.x, wb.y), pk(wb.z, wb.w)};
    *(uint4*)&Ws[oW][cW0] = uw;
    ushort tx[8];
    #pragma unroll
    for (int j = 0; j < 8; j++)
      tx[j] = qkvb[(size_t)(b * 3 * C + k0 + cX0 + j) * HW + n0 + nX];
    uint4 ux;
    ux.x = tx[0] | ((uint)tx[1] << 16);
    ux.y = tx[2] | ((uint)tx[3] << 16);
    ux.z = tx[4] | ((uint)tx[5] << 16);
    ux.w = tx[6] | ((uint)tx[7] << 16);
    *(uint4*)&Xs[nX][cX0] = ux;
    __syncthreads();

    bf16x8 af = *(const bf16x8*)&Ws[wv * 16 + li][g * 8];
    #pragma unroll
    for (int nt = 0; nt < 4; nt++) {
      bf16x8 bfr = *(const bf16x8*)&Xs[nt * 16 + li][g * 8];
      acc[nt] = __builtin_amdgcn_mfma_f32_16x16x32_bf16(af, bfr, acc[nt], 0, 0, 0);
    }
  }
  const int ob = m0 + wv * 16 + g * 4;
  #pragma unroll
  for (int r = 0; r < 4; r++) {
    float bi = bias[ob + r];
    #pragma unroll
    for (int nt = 0; nt < 4; nt++) {
      size_t idx = (size_t)(b * C + ob + r) * HW + n0 + nt * 16 + li;
      out[idx] = acc[nt][r] + bi + bf2f(xnb[idx]);
    }
  }
}

extern "C" void kernel_launch(void* const* d_in, const int* in_sizes, int n_in,
                              void* d_out, int out_size, void* d_ws, size_t ws_size,
                              hipStream_t stream) {
  const float* x     = (const float*)d_in[0];
  const float* gn_w  = (const float*)d_in[1];
  const float* gn_b  = (const float*)d_in[2];
  const float* qkv_w = (const float*)d_in[3];
  const float* qkv_b = (const float*)d_in[4];
  const float* pw    = (const float*)d_in[5];
  const float* pb    = (const float*)d_in[6];
  float* out = (float*)d_out;

  float*  stats = (float*)d_ws;                              // 512 floats (pad to 4 KB)
  ushort* xnb   = (ushort*)((char*)d_ws + 4096);             // 4 MB  bf16 [b][c][hw]
  ushort* qkvb  = xnb + (size_t)BATCH * C * HW;              // 12 MB bf16
  ushort* kt    = qkvb + (size_t)BATCH * 3 * C * HW;         // 4 MB  [bh][e][c]

  gn_part<<<dim3(256), dim3(256), 0, stream>>>(x, stats);
  gn_apply<<<dim3(C, BATCH), dim3(256), 0, stream>>>(x, gn_w, gn_b, stats, xnb);
  qkv_gemm<<<dim3(HW / 64, 6, BATCH), dim3(256), 0, stream>>>(xnb, qkv_w, qkv_b, qkvb);
  kvprep_kernel<<<dim3(HW / 64, BATCH * NH), dim3(256), 0, stream>>>(qkvb, kt);
  attn_kernel<<<dim3(HW / 256, BATCH * NH), dim3(256), 0, stream>>>(qkvb, kt);
  proj_gemm<<<dim3(HW / 64, 2, BATCH), dim3(256), 0, stream>>>(qkvb, pw, pb, xnb, out);
}

// Round 8
// 147.190 us; speedup vs baseline: 19.0028x; 1.2590x over previous
//
#include <hip/hip_runtime.h>
#include <math.h>

#define BATCH 4
#define C 128
#define HW 4096
#define G 8
#define CPG 16
#define NH 4
#define HD 32
#define EPS 1e-5f
#define SCALE 0.08838834764831845f   // 128^-0.5
#define LOG2E 1.44269504088896340f

typedef unsigned int uint;
typedef unsigned short ushort;
typedef __attribute__((ext_vector_type(8))) short bf16x8;   // 8 bf16 (4 VGPRs)
typedef __attribute__((ext_vector_type(4))) float f32x4;

__device__ __forceinline__ ushort f2bf(float x) {
  uint u = __float_as_uint(x);
  u += 0x7fff + ((u >> 16) & 1);   // RNE
  return (ushort)(u >> 16);
}
__device__ __forceinline__ ushort f2bf_r(float x) {   // round-half-away, 2 insts
  return (ushort)((__float_as_uint(x) + 0x8000u) >> 16);
}
__device__ __forceinline__ float bf2f(ushort h) {
  return __uint_as_float(((uint)h) << 16);
}
__device__ __forceinline__ uint pk(float a, float b) {  // 2 bf16 pack, round-half-away
  uint ua = __float_as_uint(a) + 0x8000u;
  uint ub = __float_as_uint(b) + 0x8000u;
  return __builtin_amdgcn_perm(ub, ua, 0x07060302);
}
__device__ __forceinline__ bf16x8 as_bf(uint4 u) {
  union { uint4 a; bf16x8 b; } x; x.a = u; return x.b;
}
__device__ __forceinline__ float fexp2(float x) {
#if __has_builtin(__builtin_amdgcn_exp2f)
  return __builtin_amdgcn_exp2f(x);   // raw v_exp_f32
#else
  return __exp2f(x);
#endif
}

// ---------------- GN pass 1: deterministic partials, plain stores ----------------
__global__ __launch_bounds__(256) void gn_part(
    const float* __restrict__ x, float* __restrict__ stats) {
  const int bg = blockIdx.x >> 3, chunk = blockIdx.x & 7;
  const float* xp = x + (size_t)bg * (CPG * HW) + chunk * 8192;
  const int tid = threadIdx.x;
  float s = 0.f, ss = 0.f;
  #pragma unroll
  for (int j = 0; j < 8; j++) {
    float4 v = ((const float4*)xp)[j * 256 + tid];
    s += (v.x + v.y) + (v.z + v.w);
    ss += (v.x * v.x + v.y * v.y) + (v.z * v.z + v.w * v.w);
  }
  #pragma unroll
  for (int off = 32; off; off >>= 1) {
    s  += __shfl_down(s, off);
    ss += __shfl_down(ss, off);
  }
  __shared__ float rs[4], rss[4];
  const int lane = tid & 63, wid = tid >> 6;
  if (lane == 0) { rs[wid] = s; rss[wid] = ss; }
  __syncthreads();
  if (tid == 0) {
    stats[(bg * 8 + chunk) * 2]     = (rs[0] + rs[1]) + (rs[2] + rs[3]);
    stats[(bg * 8 + chunk) * 2 + 1] = (rss[0] + rss[1]) + (rss[2] + rss[3]);
  }
}

// ---------------- GN pass 2: reduce 8 partials, normalize, write bf16 xn ----------------
__global__ __launch_bounds__(256) void gn_apply(
    const float* __restrict__ x, const float* __restrict__ w,
    const float* __restrict__ b, const float* __restrict__ stats,
    ushort* __restrict__ xnb) {
  const int c = blockIdx.x, batch = blockIdx.y;
  const int bg = batch * G + (c >> 4);
  float s = 0.f, ss = 0.f;
  #pragma unroll
  for (int k = 0; k < 8; k++) {
    s  += stats[(bg * 8 + k) * 2];
    ss += stats[(bg * 8 + k) * 2 + 1];
  }
  const float mean = s * (1.0f / 65536.0f);
  const float var  = ss * (1.0f / 65536.0f) - mean * mean;
  const float inv  = rsqrtf(var + EPS);
  const float ca = w[c] * inv;
  const float cb = b[c] - mean * ca;
  const size_t base = ((size_t)batch * C + c) * HW;
  const float* xp = x + base;
  ushort* op = xnb + base;
  const int tid = threadIdx.x;
  #pragma unroll
  for (int j = 0; j < 4; j++) {
    int i = (j * 256 + tid) * 4;
    float4 v = *(const float4*)&xp[i];
    uint2 u;
    u.x = pk(fmaf(v.x, ca, cb), fmaf(v.y, ca, cb));
    u.y = pk(fmaf(v.z, ca, cb), fmaf(v.w, ca, cb));
    *(uint2*)&op[i] = u;
  }
}

// ---------------- MFMA GEMM: qkv = W(384x128) @ xn(128 x HW), bf16 in/out ----------------
__global__ __launch_bounds__(256) void qkv_gemm(
    const ushort* __restrict__ xnb, const float* __restrict__ w,
    const float* __restrict__ bias, ushort* __restrict__ qkvb) {
  const int b = blockIdx.z, m0 = blockIdx.y * 64, n0 = blockIdx.x * 64;
  const int tid = threadIdx.x, lane = tid & 63, wv = tid >> 6;
  const int li = lane & 15, g = lane >> 4;
  __shared__ ushort Ws[64][40];
  __shared__ ushort Xs[64][40];

  f32x4 acc[4];
  #pragma unroll
  for (int nt = 0; nt < 4; nt++) acc[nt] = (f32x4){0.f, 0.f, 0.f, 0.f};

  const int oW = tid >> 2, cW0 = (tid & 3) * 8;
  const int nX = tid & 63, cX0 = (tid >> 6) * 8;

  for (int k0 = 0; k0 < C; k0 += 32) {
    __syncthreads();
    float4 wa = *(const float4*)&w[(size_t)(m0 + oW) * C + k0 + cW0];
    float4 wb = *(const float4*)&w[(size_t)(m0 + oW) * C + k0 + cW0 + 4];
    uint4 uw = {pk(wa.x, wa.y), pk(wa.z, wa.w), pk(wb.x, wb.y), pk(wb.z, wb.w)};
    *(uint4*)&Ws[oW][cW0] = uw;
    ushort tx[8];
    #pragma unroll
    for (int j = 0; j < 8; j++)
      tx[j] = xnb[(size_t)(b * C + k0 + cX0 + j) * HW + n0 + nX];
    uint4 ux;
    ux.x = tx[0] | ((uint)tx[1] << 16);
    ux.y = tx[2] | ((uint)tx[3] << 16);
    ux.z = tx[4] | ((uint)tx[5] << 16);
    ux.w = tx[6] | ((uint)tx[7] << 16);
    *(uint4*)&Xs[nX][cX0] = ux;
    __syncthreads();

    bf16x8 af = *(const bf16x8*)&Ws[wv * 16 + li][g * 8];
    #pragma unroll
    for (int nt = 0; nt < 4; nt++) {
      bf16x8 bfr = *(const bf16x8*)&Xs[nt * 16 + li][g * 8];
      acc[nt] = __builtin_amdgcn_mfma_f32_16x16x32_bf16(af, bfr, acc[nt], 0, 0, 0);
    }
  }
  const int ob = m0 + wv * 16 + g * 4;
  #pragma unroll
  for (int r = 0; r < 4; r++) {
    float bi = bias[ob + r];
    #pragma unroll
    for (int nt = 0; nt < 4; nt++) {
      qkvb[(size_t)(b * 3 * C + ob + r) * HW + n0 + nt * 16 + li] = f2bf(acc[nt][r] + bi);
    }
  }
}

// ---------------- K prep: KT[bh][e][c] (c contiguous), vectorized ----------------
__global__ __launch_bounds__(256) void kvprep_kernel(
    const ushort* __restrict__ qkvb, ushort* __restrict__ kt) {
  const int bh = blockIdx.y, b = bh >> 2, h = bh & 3;
  const int e0 = blockIdx.x * 64;
  const ushort* kp = qkvb + (size_t)(b * 3 * C + C + h * HD) * HW;
  ushort* ktp = kt + (size_t)bh * HW * HD;
  const int t = threadIdx.x;

  __shared__ ushort Kt[32][66];
  {
    const int c = t >> 3, e8 = (t & 7) * 8;
    *(uint4*)&Kt[c][e8] = *(const uint4*)&kp[(size_t)c * HW + e0 + e8];
  }
  __syncthreads();
  {
    const int e = t >> 2, c0 = (t & 3) * 8;
    ushort o[8];
    #pragma unroll
    for (int j = 0; j < 8; j++) o[j] = Kt[c0 + j][e];
    uint4 u;
    u.x = o[0] | ((uint)o[1] << 16);
    u.y = o[2] | ((uint)o[3] << 16);
    u.z = o[4] | ((uint)o[5] << 16);
    u.w = o[6] | ((uint)o[7] << 16);
    *(uint4*)&ktp[(size_t)(e0 + e) * HD + c0] = u;
  }
}

// ---------------- MFMA flash attention: LDS-shared K/V + split-K 2-way, 8-wave blocks ----------------
// block = 8 waves x 32 q = 128 q. Wave-group A (waves 0-3) does keys 0..2047,
// group B (waves 4-7) keys 2048..4095; each group shares a double-buffered LDS
// K/V tile stream (4 waves per 4 KB tile). Merge: partner-wave (w ^ 4) partial
// exchange via LDS; no-max softmax makes it a pure (O, l) add.
// S^T = K^T Q; P stays in registers (sigma absorbed in V ds_read addressing).
__global__ __launch_bounds__(512, 4) void attn_kernel(
    ushort* __restrict__ qkv, const ushort* __restrict__ kt) {
  const int bh = blockIdx.y, b = bh >> 2, h = bh & 3;
  const int tid = threadIdx.x, lane = tid & 63, wv = tid >> 6;
  const int li = lane & 15, g = lane >> 4;
  const int grp = wv >> 2, w4 = wv & 3;
  ushort* qp = qkv + (size_t)(b * 3 * C + h * HD) * HW;
  const ushort* vpl = qkv + (size_t)(b * 3 * C + 2 * C + h * HD) * HW;
  const ushort* ktp = kt + (size_t)bh * HW * HD;
  const int d0 = blockIdx.x * 128 + w4 * 32;

  __shared__ ushort Ks[2][2][32][40];   // [grp][buf][e][c]
  __shared__ ushort Vs[2][2][32][40];   // [grp][buf][c][e]
  __shared__ float OP[8][64][19];       // merge: 16 O + 2 l, odd pitch

  // Q B-fragments (2 d-tiles), prescaled by SCALE*log2(e)
  const float qs = SCALE * LOG2E;
  bf16x8 qf[2];
  #pragma unroll
  for (int dt = 0; dt < 2; dt++) {
    int d = d0 + dt * 16 + li;
    float qv[8];
    #pragma unroll
    for (int j = 0; j < 8; j++)
      qv[j] = bf2f(qp[(size_t)(g * 8 + j) * HW + d]) * qs;
    uint4 qu = {pk(qv[0], qv[1]), pk(qv[2], qv[3]), pk(qv[4], qv[5]), pk(qv[6], qv[7])};
    qf[dt] = as_bf(qu);
  }

  f32x4 O[2][2];
  #pragma unroll
  for (int dt = 0; dt < 2; dt++)
    #pragma unroll
    for (int ct = 0; ct < 2; ct++) O[dt][ct] = (f32x4){0.f, 0.f, 0.f, 0.f};
  f32x4 lacc[2] = {(f32x4){0.f, 0.f, 0.f, 0.f}, (f32x4){0.f, 0.f, 0.f, 0.f}};
  const uint one2 = 0x3F803F80u;
  const bf16x8 ones = as_bf((uint4){one2, one2, one2, one2});

  // staging: group-local threads 0..127 stage K, 128..255 stage V
  const int gt = tid & 255;
  const bool isK = gt < 128;
  const int t2 = gt & 127;
  const int srow = t2 >> 2, scol8 = (t2 & 3) * 8;
  const ushort* gK = ktp + (size_t)(grp * 64) * 1024 + t2 * 8;       // + n*1024
  const ushort* gV = vpl + (size_t)srow * HW + grp * 2048 + scol8;   // + n*32

  uint4 st = isK ? *(const uint4*)&gK[0] : *(const uint4*)&gV[0];
  if (isK) *(uint4*)&Ks[grp][0][srow][scol8] = st;
  else     *(uint4*)&Vs[grp][0][srow][scol8] = st;
  st = isK ? *(const uint4*)&gK[1024] : *(const uint4*)&gV[32];
  __syncthreads();

  for (int it = 0; it < 64; it++) {
    const int cur = it & 1, nxt = cur ^ 1;
    // store tile it+1 (loaded last iter) into the other buffer
    if (isK) *(uint4*)&Ks[grp][nxt][srow][scol8] = st;
    else     *(uint4*)&Vs[grp][nxt][srow][scol8] = st;

    // fragments from current buffer
    bf16x8 kf0 = *(const bf16x8*)&Ks[grp][cur][li][g * 8];
    bf16x8 kf1 = *(const bf16x8*)&Ks[grp][cur][16 + li][g * 8];
    uint2 va0 = *(const uint2*)&Vs[grp][cur][li][4 * g];
    uint2 va1 = *(const uint2*)&Vs[grp][cur][li][16 + 4 * g];
    uint2 vb0 = *(const uint2*)&Vs[grp][cur][16 + li][4 * g];
    uint2 vb1 = *(const uint2*)&Vs[grp][cur][16 + li][16 + 4 * g];
    bf16x8 vf0 = as_bf((uint4){va0.x, va0.y, va1.x, va1.y});
    bf16x8 vf1 = as_bf((uint4){vb0.x, vb0.y, vb1.x, vb1.y});

    // prefetch tile it+2 into regs (wraps in-range on last iters: dead data)
    const int tn = (it + 2) & 63;
    st = isK ? *(const uint4*)&gK[(size_t)tn * 1024] : *(const uint4*)&gV[tn * 32];

    const f32x4 z = (f32x4){0.f, 0.f, 0.f, 0.f};
    #pragma unroll
    for (int dt = 0; dt < 2; dt++) {
      f32x4 s0 = __builtin_amdgcn_mfma_f32_16x16x32_bf16(kf0, qf[dt], z, 0, 0, 0);
      f32x4 s1 = __builtin_amdgcn_mfma_f32_16x16x32_bf16(kf1, qf[dt], z, 0, 0, 0);
      float p0 = fexp2(s0[0]), p1 = fexp2(s0[1]), p2 = fexp2(s0[2]), p3 = fexp2(s0[3]);
      float p4 = fexp2(s1[0]), p5 = fexp2(s1[1]), p6 = fexp2(s1[2]), p7 = fexp2(s1[3]);
      // sigma: k=g*8+{0..3} -> e=4g+{0..3}; k=g*8+{4..7} -> e=16+4g+{0..3}
      uint4 pu = {pk(p0, p1), pk(p2, p3), pk(p4, p5), pk(p6, p7)};
      bf16x8 pf = as_bf(pu);
      lacc[dt] = __builtin_amdgcn_mfma_f32_16x16x32_bf16(ones, pf, lacc[dt], 0, 0, 0);
      O[dt][0] = __builtin_amdgcn_mfma_f32_16x16x32_bf16(vf0, pf, O[dt][0], 0, 0, 0);
      O[dt][1] = __builtin_amdgcn_mfma_f32_16x16x32_bf16(vf1, pf, O[dt][1], 0, 0, 0);
    }
    __syncthreads();
  }

  // ---- split-K merge with partner wave (w ^ 4); wave writes channel half ct=grp ----
  #pragma unroll
  for (int dt = 0; dt < 2; dt++) {
    #pragma unroll
    for (int ct = 0; ct < 2; ct++)
      #pragma unroll
      for (int r = 0; r < 4; r++) OP[wv][lane][dt * 8 + ct * 4 + r] = O[dt][ct][r];
    OP[wv][lane][16 + dt] = lacc[dt][0];
  }
  __syncthreads();
  const int pw = wv ^ 4;
  #pragma unroll
  for (int dt = 0; dt < 2; dt++) {
    const float inv = 1.0f / (lacc[dt][0] + OP[pw][lane][16 + dt]);
    const int d = d0 + dt * 16 + li;
    #pragma unroll
    for (int r = 0; r < 4; r++) {
      float val = O[dt][grp][r] + OP[pw][lane][dt * 8 + grp * 4 + r];
      qp[(size_t)(grp * 16 + g * 4 + r) * HW + d] = f2bf_r(val * inv);
    }
  }
}

// ---------------- MFMA GEMM proj + bias + bf16 residual, fp32 out ----------------
__global__ __launch_bounds__(256) void proj_gemm(
    const ushort* __restrict__ qkvb, const float* __restrict__ w,
    const float* __restrict__ bias, const ushort* __restrict__ xnb, float* __restrict__ out) {
  const int b = blockIdx.z, m0 = blockIdx.y * 64, n0 = blockIdx.x * 64;
  const int tid = threadIdx.x, lane = tid & 63, wv = tid >> 6;
  const int li = lane & 15, g = lane >> 4;
  __shared__ ushort Ws[64][40];
  __shared__ ushort Xs[64][40];

  f32x4 acc[4];
  #pragma unroll
  for (int nt = 0; nt < 4; nt++) acc[nt] = (f32x4){0.f, 0.f, 0.f, 0.f};

  const int oW = tid >> 2, cW0 = (tid & 3) * 8;
  const int nX = tid & 63, cX0 = (tid >> 6) * 8;

  for (int k0 = 0; k0 < C; k0 += 32) {
    __syncthreads();
    float4 wa = *(const float4*)&w[(size_t)(m0 + oW) * C + k0 + cW0];
    float4 wb = *(const float4*)&w[(size_t)(m0 + oW) * C + k0 + cW0 + 4];
    uint4 uw = {pk(wa.x, wa.y), pk(wa.z, wa.w), pk(wb.x, wb.y), pk(wb.z, wb.w)};
    *(uint4*)&Ws[oW][cW0] = uw;
    ushort tx[8];
    #pragma unroll
    for (int j = 0; j < 8; j++)
      tx[j] = qkvb[(size_t)(b * 3 * C + k0 + cX0 + j) * HW + n0 + nX];
    uint4 ux;
    ux.x = tx[0] | ((uint)tx[1] << 16);
    ux.y = tx[2] | ((uint)tx[3] << 16);
    ux.z = tx[4] | ((uint)tx[5] << 16);
    ux.w = tx[6] | ((uint)tx[7] << 16);
    *(uint4*)&Xs[nX][cX0] = ux;
    __syncthreads();

    bf16x8 af = *(const bf16x8*)&Ws[wv * 16 + li][g * 8];
    #pragma unroll
    for (int nt = 0; nt < 4; nt++) {
      bf16x8 bfr = *(const bf16x8*)&Xs[nt * 16 + li][g * 8];
      acc[nt] = __builtin_amdgcn_mfma_f32_16x16x32_bf16(af, bfr, acc[nt], 0, 0, 0);
    }
  }
  const int ob = m0 + wv * 16 + g * 4;
  #pragma unroll
  for (int r = 0; r < 4; r++) {
    float bi = bias[ob + r];
    #pragma unroll
    for (int nt = 0; nt < 4; nt++) {
      size_t idx = (size_t)(b * C + ob + r) * HW + n0 + nt * 16 + li;
      out[idx] = acc[nt][r] + bi + bf2f(xnb[idx]);
    }
  }
}

extern "C" void kernel_launch(void* const* d_in, const int* in_sizes, int n_in,
                              void* d_out, int out_size, void* d_ws, size_t ws_size,
                              hipStream_t stream) {
  const float* x     = (const float*)d_in[0];
  const float* gn_w  = (const float*)d_in[1];
  const float* gn_b  = (const float*)d_in[2];
  const float* qkv_w = (const float*)d_in[3];
  const float* qkv_b = (const float*)d_in[4];
  const float* pw    = (const float*)d_in[5];
  const float* pb    = (const float*)d_in[6];
  float* out = (float*)d_out;

  float*  stats = (float*)d_ws;                              // 512 floats (pad to 4 KB)
  ushort* xnb   = (ushort*)((char*)d_ws + 4096);             // 4 MB  bf16 [b][c][hw]
  ushort* qkvb  = xnb + (size_t)BATCH * C * HW;              // 12 MB bf16
  ushort* kt    = qkvb + (size_t)BATCH * 3 * C * HW;         // 4 MB  [bh][e][c]

  gn_part<<<dim3(256), dim3(256), 0, stream>>>(x, stats);
  gn_apply<<<dim3(C, BATCH), dim3(256), 0, stream>>>(x, gn_w, gn_b, stats, xnb);
  qkv_gemm<<<dim3(HW / 64, 6, BATCH), dim3(256), 0, stream>>>(xnb, qkv_w, qkv_b, qkvb);
  kvprep_kernel<<<dim3(HW / 64, BATCH * NH), dim3(256), 0, stream>>>(qkvb, kt);
  attn_kernel<<<dim3(HW / 128, BATCH * NH), dim3(512), 0, stream>>>(qkvb, kt);
  proj_gemm<<<dim3(HW / 64, 2, BATCH), dim3(256), 0, stream>>>(qkvb, pw, pb, xnb, out);
}